// Round 1
// baseline (3760.369 us; speedup 1.0000x reference)
//
#include <hip/hip_runtime.h>

// GCN_80376017977701: 3-layer GCN, N=100000 nodes, E=1600000 edges,
// dims 64 -> 64 -> 64 -> 32, symmetric norm with self-loops, leaky_relu(0.01)
// between layers. Outputs: emb1 [N,64], emb2 [N,64], emb3 [N,32] concat in d_out.

constexpr int N_NODES = 100000;
constexpr int N_EDGES = 1600000;
constexpr float NEG = 0.01f;

// ---- degree count over dst (self-loop added analytically later) ----
__global__ void count_kernel(const int* __restrict__ dst, int* __restrict__ cnt) {
    int e = blockIdx.x * blockDim.x + threadIdx.x;
    if (e < N_EDGES) atomicAdd(&cnt[dst[e]], 1);
}

__global__ void disq_kernel(const int* __restrict__ cnt, float* __restrict__ disq) {
    int i = blockIdx.x * blockDim.x + threadIdx.x;
    if (i < N_NODES) disq[i] = rsqrtf(1.0f + (float)cnt[i]);
}

__global__ void norm_kernel(const int* __restrict__ src, const int* __restrict__ dst,
                            const float* __restrict__ disq, float* __restrict__ nrm) {
    int e = blockIdx.x * blockDim.x + threadIdx.x;
    if (e < N_EDGES) nrm[e] = disq[src[e]] * disq[dst[e]];
}

// ---- h = x @ W ; W staged in LDS; one thread per (node, out-col) ----
template <int D_IN, int D_OUT>
__global__ void linear_kernel(const float* __restrict__ x, const float* __restrict__ W,
                              float* __restrict__ h) {
    __shared__ float sW[D_IN * D_OUT];
    for (int i = threadIdx.x; i < D_IN * D_OUT; i += blockDim.x) sW[i] = W[i];
    __syncthreads();
    int t = blockIdx.x * blockDim.x + threadIdx.x;
    int node = t / D_OUT;
    int col  = t % D_OUT;
    if (node >= N_NODES) return;
    const float* xr = x + (size_t)node * D_IN;
    float acc = 0.f;
#pragma unroll
    for (int k = 0; k < D_IN; ++k) acc = fmaf(xr[k], sW[k * D_OUT + col], acc);
    h[(size_t)node * D_OUT + col] = acc;
}

// ---- edge-parallel scatter-add: agg[dst] += h[src] * nrm ----
// D/4 threads per edge, each handles 4 consecutive columns (float4 gather).
template <int D>
__global__ void aggregate_kernel(const int* __restrict__ src, const int* __restrict__ dst,
                                 const float* __restrict__ nrm, const float* __restrict__ h,
                                 float* __restrict__ agg) {
    constexpr int TPE = D / 4;
    long long t = (long long)blockIdx.x * blockDim.x + threadIdx.x;
    int e = (int)(t / TPE);
    if (e >= N_EDGES) return;
    int part = (int)(t % TPE);
    int s = src[e];
    int d = dst[e];
    float w = nrm[e];
    const float4 v = *reinterpret_cast<const float4*>(h + (size_t)s * D + part * 4);
    float* o = agg + (size_t)d * D + part * 4;
    atomicAdd(o + 0, v.x * w);
    atomicAdd(o + 1, v.y * w);
    atomicAdd(o + 2, v.z * w);
    atomicAdd(o + 3, v.w * w);
}

// ---- out = [leaky_relu](agg + h*disq^2 + b) ----
template <int D, bool RELU>
__global__ void finish_kernel(const float* __restrict__ agg, const float* __restrict__ h,
                              const float* __restrict__ disq, const float* __restrict__ b,
                              float* __restrict__ out) {
    int t = blockIdx.x * blockDim.x + threadIdx.x;
    if (t >= N_NODES * D) return;
    int node = t / D;
    int col  = t % D;
    float di = disq[node];
    float v = agg[t] + h[t] * di * di + b[col];
    if (RELU) v = (v >= 0.f) ? v : NEG * v;
    out[t] = v;
}

extern "C" void kernel_launch(void* const* d_in, const int* in_sizes, int n_in,
                              void* d_out, int out_size, void* d_ws, size_t ws_size,
                              hipStream_t stream) {
    const float* x  = (const float*)d_in[0];
    const int* ei   = (const int*)d_in[1];
    const int* src  = ei;            // edge_index[0]
    const int* dst  = ei + N_EDGES;  // edge_index[1]
    const float* W1 = (const float*)d_in[2];
    const float* b1 = (const float*)d_in[3];
    const float* W2 = (const float*)d_in[4];
    const float* b2 = (const float*)d_in[5];
    const float* W3 = (const float*)d_in[6];
    const float* b3 = (const float*)d_in[7];

    float* out  = (float*)d_out;
    float* emb1 = out;                          // N x 64
    float* emb2 = out + (size_t)N_NODES * 64;   // N x 64
    float* emb3 = out + (size_t)N_NODES * 128;  // N x 32

    char* ws = (char*)d_ws;
    int*   cnt  = (int*)ws;    ws += sizeof(int)   * N_NODES;
    float* disq = (float*)ws;  ws += sizeof(float) * N_NODES;
    float* nrm  = (float*)ws;  ws += sizeof(float) * N_EDGES;
    float* h    = (float*)ws;  ws += sizeof(float) * (size_t)N_NODES * 64;
    float* agg  = (float*)ws;  ws += sizeof(float) * (size_t)N_NODES * 64;

    const int BLK = 256;
    const int gE   = (N_EDGES + BLK - 1) / BLK;
    const int gN   = (N_NODES + BLK - 1) / BLK;
    const int gN64 = (N_NODES * 64 + BLK - 1) / BLK;
    const int gN32 = (N_NODES * 32 + BLK - 1) / BLK;
    const int gE16 = (int)(((long long)N_EDGES * 16 + BLK - 1) / BLK);
    const int gE8  = (int)(((long long)N_EDGES * 8  + BLK - 1) / BLK);

    // normalization coefficients
    hipMemsetAsync(cnt, 0, sizeof(int) * N_NODES, stream);
    count_kernel<<<gE, BLK, 0, stream>>>(dst, cnt);
    disq_kernel<<<gN, BLK, 0, stream>>>(cnt, disq);
    norm_kernel<<<gE, BLK, 0, stream>>>(src, dst, disq, nrm);

    // ---- layer 1: x[64] -> emb1[64], leaky_relu ----
    linear_kernel<64, 64><<<gN64, BLK, 0, stream>>>(x, W1, h);
    hipMemsetAsync(agg, 0, sizeof(float) * (size_t)N_NODES * 64, stream);
    aggregate_kernel<64><<<gE16, BLK, 0, stream>>>(src, dst, nrm, h, agg);
    finish_kernel<64, true><<<gN64, BLK, 0, stream>>>(agg, h, disq, b1, emb1);

    // ---- layer 2: emb1[64] -> emb2[64], leaky_relu ----
    linear_kernel<64, 64><<<gN64, BLK, 0, stream>>>(emb1, W2, h);
    hipMemsetAsync(agg, 0, sizeof(float) * (size_t)N_NODES * 64, stream);
    aggregate_kernel<64><<<gE16, BLK, 0, stream>>>(src, dst, nrm, h, agg);
    finish_kernel<64, true><<<gN64, BLK, 0, stream>>>(agg, h, disq, b2, emb2);

    // ---- layer 3: emb2[64] -> emb3[32], no activation ----
    linear_kernel<64, 32><<<gN32, BLK, 0, stream>>>(emb2, W3, h);
    hipMemsetAsync(agg, 0, sizeof(float) * (size_t)N_NODES * 32, stream);
    aggregate_kernel<32><<<gE8, BLK, 0, stream>>>(src, dst, nrm, h, agg);
    finish_kernel<32, false><<<gN32, BLK, 0, stream>>>(agg, h, disq, b3, emb3);
}

// Round 2
// 649.067 us; speedup vs baseline: 5.7935x; 5.7935x over previous
//
#include <hip/hip_runtime.h>

// GCN_80376017977701: 3-layer GCN, N=100000, E=1600000, dims 64->64->64->32,
// symmetric norm with self-loops, leaky_relu(0.01) between layers.
// R2: CSR-based gather aggregation (no fp32 atomics in hot path).
//   - build CSR once: degree count -> exclusive scan -> scatter fill (src, norm)
//   - per layer: linear (LDS-staged) -> gather_finish (register accumulate,
//     fused self-loop + bias + leaky_relu, direct write to d_out slice)

constexpr int N_NODES = 100000;
constexpr int N_EDGES = 1600000;
constexpr float NEG = 0.01f;

constexpr int SCAN_BLK = 256;
constexpr int NBLK = (N_NODES + SCAN_BLK - 1) / SCAN_BLK;  // 391 (<512)

// ---- degree count over dst (self-loop handled analytically) ----
__global__ void count_kernel(const int* __restrict__ dst, int* __restrict__ cnt) {
    int e = blockIdx.x * blockDim.x + threadIdx.x;
    if (e < N_EDGES) atomicAdd(&cnt[dst[e]], 1);
}

__global__ void disq_kernel(const int* __restrict__ cnt, float* __restrict__ disq) {
    int i = blockIdx.x * blockDim.x + threadIdx.x;
    if (i < N_NODES) disq[i] = rsqrtf(1.0f + (float)cnt[i]);
}

// ---- exclusive scan of cnt -> rowptr (3 kernels) ----
__global__ void scan1_kernel(const int* __restrict__ cnt, int* __restrict__ tmp,
                             int* __restrict__ bsum) {
    __shared__ int s[SCAN_BLK];
    int i = blockIdx.x * SCAN_BLK + threadIdx.x;
    int v = (i < N_NODES) ? cnt[i] : 0;
    s[threadIdx.x] = v;
    __syncthreads();
    for (int off = 1; off < SCAN_BLK; off <<= 1) {
        int t = (threadIdx.x >= off) ? s[threadIdx.x - off] : 0;
        __syncthreads();
        s[threadIdx.x] += t;
        __syncthreads();
    }
    if (i < N_NODES) tmp[i] = s[threadIdx.x] - v;  // exclusive within block
    if (threadIdx.x == SCAN_BLK - 1) bsum[blockIdx.x] = s[threadIdx.x];
}

__global__ void scan2_kernel(int* __restrict__ bsum) {  // single block of 512
    __shared__ int s[512];
    int v = (threadIdx.x < NBLK) ? bsum[threadIdx.x] : 0;
    s[threadIdx.x] = v;
    __syncthreads();
    for (int off = 1; off < 512; off <<= 1) {
        int t = (threadIdx.x >= off) ? s[threadIdx.x - off] : 0;
        __syncthreads();
        s[threadIdx.x] += t;
        __syncthreads();
    }
    if (threadIdx.x < NBLK) bsum[threadIdx.x] = s[threadIdx.x] - v;  // exclusive
}

__global__ void scan3_kernel(const int* __restrict__ tmp, const int* __restrict__ bsum,
                             int* __restrict__ rowptr, int* __restrict__ cursor) {
    int i = blockIdx.x * blockDim.x + threadIdx.x;
    if (i < N_NODES) {
        int r = tmp[i] + bsum[i / SCAN_BLK];
        rowptr[i] = r;
        cursor[i] = r;
    }
    if (i == N_NODES) rowptr[N_NODES] = N_EDGES;
}

// ---- scatter edges into CSR slots, with fused norm weight ----
__global__ void fill_csr_kernel(const int* __restrict__ src, const int* __restrict__ dst,
                                const float* __restrict__ disq, int* __restrict__ cursor,
                                int* __restrict__ csr_src, float* __restrict__ csr_w) {
    int e = blockIdx.x * blockDim.x + threadIdx.x;
    if (e >= N_EDGES) return;
    int s = src[e];
    int d = dst[e];
    int pos = atomicAdd(&cursor[d], 1);
    csr_src[pos] = s;
    csr_w[pos] = disq[s] * disq[d];
}

// ---- h = x @ W ; W and x-rows staged in LDS ----
template <int D_IN, int D_OUT>
__global__ void linear_kernel(const float* __restrict__ x, const float* __restrict__ W,
                              float* __restrict__ h) {
    constexpr int NPB = 256 / D_OUT;  // nodes per block
    __shared__ float sW[D_IN * D_OUT];
    __shared__ float sx[NPB][D_IN];
    for (int i = threadIdx.x; i < D_IN * D_OUT; i += 256) sW[i] = W[i];
    int local = threadIdx.x / D_OUT;
    int col   = threadIdx.x % D_OUT;
    int node  = blockIdx.x * NPB + local;
    if (node < N_NODES) {
        for (int k = col; k < D_IN; k += D_OUT) sx[local][k] = x[(size_t)node * D_IN + k];
    }
    __syncthreads();
    if (node >= N_NODES) return;
    float acc = 0.f;
#pragma unroll
    for (int k = 0; k < D_IN; ++k) acc = fmaf(sx[local][k], sW[k * D_OUT + col], acc);
    h[(size_t)node * D_OUT + col] = acc;
}

// ---- gather-reduce + fused finish: out = [relu](sum_nbr w*h[src] + h*disq^2 + b) ----
template <int D, bool RELU>
__global__ void gather_finish_kernel(const int* __restrict__ rowptr,
                                     const int* __restrict__ csr_src,
                                     const float* __restrict__ csr_w,
                                     const float* __restrict__ h,
                                     const float* __restrict__ disq,
                                     const float* __restrict__ b,
                                     float* __restrict__ out) {
    constexpr int TPN = D / 4;  // threads per node
    int t = blockIdx.x * blockDim.x + threadIdx.x;
    int node = t / TPN;
    if (node >= N_NODES) return;
    int part = t % TPN;
    int beg = rowptr[node];
    int end = rowptr[node + 1];
    float4 acc = {0.f, 0.f, 0.f, 0.f};
    for (int j = beg; j < end; ++j) {
        int s = csr_src[j];
        float w = csr_w[j];
        const float4 v = *reinterpret_cast<const float4*>(h + (size_t)s * D + part * 4);
        acc.x = fmaf(v.x, w, acc.x);
        acc.y = fmaf(v.y, w, acc.y);
        acc.z = fmaf(v.z, w, acc.z);
        acc.w = fmaf(v.w, w, acc.w);
    }
    float di = disq[node];
    float dw = di * di;
    const float4 hv = *reinterpret_cast<const float4*>(h + (size_t)node * D + part * 4);
    const float4 bv = *reinterpret_cast<const float4*>(b + part * 4);
    acc.x = fmaf(hv.x, dw, acc.x) + bv.x;
    acc.y = fmaf(hv.y, dw, acc.y) + bv.y;
    acc.z = fmaf(hv.z, dw, acc.z) + bv.z;
    acc.w = fmaf(hv.w, dw, acc.w) + bv.w;
    if (RELU) {
        acc.x = (acc.x >= 0.f) ? acc.x : NEG * acc.x;
        acc.y = (acc.y >= 0.f) ? acc.y : NEG * acc.y;
        acc.z = (acc.z >= 0.f) ? acc.z : NEG * acc.z;
        acc.w = (acc.w >= 0.f) ? acc.w : NEG * acc.w;
    }
    *reinterpret_cast<float4*>(out + (size_t)node * D + part * 4) = acc;
}

extern "C" void kernel_launch(void* const* d_in, const int* in_sizes, int n_in,
                              void* d_out, int out_size, void* d_ws, size_t ws_size,
                              hipStream_t stream) {
    const float* x  = (const float*)d_in[0];
    const int* ei   = (const int*)d_in[1];
    const int* src  = ei;            // edge_index[0]
    const int* dst  = ei + N_EDGES;  // edge_index[1]
    const float* W1 = (const float*)d_in[2];
    const float* b1 = (const float*)d_in[3];
    const float* W2 = (const float*)d_in[4];
    const float* b2 = (const float*)d_in[5];
    const float* W3 = (const float*)d_in[6];
    const float* b3 = (const float*)d_in[7];

    float* out  = (float*)d_out;
    float* emb1 = out;                          // N x 64
    float* emb2 = out + (size_t)N_NODES * 64;   // N x 64
    float* emb3 = out + (size_t)N_NODES * 128;  // N x 32

    char* ws = (char*)d_ws;
    int*   cnt     = (int*)ws;    ws += sizeof(int)   * N_NODES;
    float* disq    = (float*)ws;  ws += sizeof(float) * N_NODES;
    int*   tmp     = (int*)ws;    ws += sizeof(int)   * N_NODES;
    int*   bsum    = (int*)ws;    ws += sizeof(int)   * 512;
    int*   rowptr  = (int*)ws;    ws += sizeof(int)   * (N_NODES + 1);
    int*   cursor  = (int*)ws;    ws += sizeof(int)   * N_NODES;
    int*   csr_src = (int*)ws;    ws += sizeof(int)   * N_EDGES;
    float* csr_w   = (float*)ws;  ws += sizeof(float) * N_EDGES;
    float* h       = (float*)ws;  ws += sizeof(float) * (size_t)N_NODES * 64;

    const int BLK = 256;
    const int gE    = (N_EDGES + BLK - 1) / BLK;
    const int gN    = (N_NODES + BLK - 1) / BLK;
    const int gN1   = (N_NODES + 1 + BLK - 1) / BLK;
    const int gN16  = (N_NODES * 16 + BLK - 1) / BLK;  // gather D=64
    const int gN8   = (N_NODES * 8  + BLK - 1) / BLK;  // gather D=32
    const int gLin64 = (N_NODES + 3) / 4;   // linear D_OUT=64: 4 nodes/block
    const int gLin32 = (N_NODES + 7) / 8;   // linear D_OUT=32: 8 nodes/block

    // ---- CSR build (once; reused by all 3 layers) ----
    hipMemsetAsync(cnt, 0, sizeof(int) * N_NODES, stream);
    count_kernel<<<gE, BLK, 0, stream>>>(dst, cnt);
    disq_kernel<<<gN, BLK, 0, stream>>>(cnt, disq);
    scan1_kernel<<<NBLK, SCAN_BLK, 0, stream>>>(cnt, tmp, bsum);
    scan2_kernel<<<1, 512, 0, stream>>>(bsum);
    scan3_kernel<<<gN1, BLK, 0, stream>>>(tmp, bsum, rowptr, cursor);
    fill_csr_kernel<<<gE, BLK, 0, stream>>>(src, dst, disq, cursor, csr_src, csr_w);

    // ---- layer 1: x[64] -> emb1[64], leaky_relu ----
    linear_kernel<64, 64><<<gLin64, BLK, 0, stream>>>(x, W1, h);
    gather_finish_kernel<64, true><<<gN16, BLK, 0, stream>>>(rowptr, csr_src, csr_w, h, disq, b1, emb1);

    // ---- layer 2: emb1[64] -> emb2[64], leaky_relu ----
    linear_kernel<64, 64><<<gLin64, BLK, 0, stream>>>(emb1, W2, h);
    gather_finish_kernel<64, true><<<gN16, BLK, 0, stream>>>(rowptr, csr_src, csr_w, h, disq, b2, emb2);

    // ---- layer 3: emb2[64] -> emb3[32], no activation ----
    linear_kernel<64, 32><<<gLin32, BLK, 0, stream>>>(emb2, W3, h);
    gather_finish_kernel<32, false><<<gN8, BLK, 0, stream>>>(rowptr, csr_src, csr_w, h, disq, b3, emb3);
}

// Round 3
// 641.082 us; speedup vs baseline: 5.8657x; 1.0125x over previous
//
#include <hip/hip_runtime.h>

// GCN_80376017977701: 3-layer GCN, N=100000, E=1600000, dims 64->64->64->32,
// symmetric norm with self-loops, leaky_relu(0.01) between layers.
// R3: CSR gather with implicit norm (no csr_w array -> half the scattered
// write traffic in fill), int4-vectorized edge reads, 2-way unrolled gather.

constexpr int N_NODES = 100000;
constexpr int N_EDGES = 1600000;
constexpr float NEG = 0.01f;

constexpr int SCAN_BLK = 256;
constexpr int NBLK = (N_NODES + SCAN_BLK - 1) / SCAN_BLK;  // 391 (<512)

// ---- degree count over dst (self-loop handled analytically); 4 edges/thread ----
__global__ void count_kernel(const int* __restrict__ dst, int* __restrict__ cnt) {
    int t = blockIdx.x * blockDim.x + threadIdx.x;
    if (t * 4 >= N_EDGES) return;
    const int4 d = *reinterpret_cast<const int4*>(dst + t * 4);
    atomicAdd(&cnt[d.x], 1);
    atomicAdd(&cnt[d.y], 1);
    atomicAdd(&cnt[d.z], 1);
    atomicAdd(&cnt[d.w], 1);
}

// ---- exclusive scan of cnt -> rowptr ----
__global__ void scan1_kernel(const int* __restrict__ cnt, int* __restrict__ tmp,
                             int* __restrict__ bsum) {
    __shared__ int s[SCAN_BLK];
    int i = blockIdx.x * SCAN_BLK + threadIdx.x;
    int v = (i < N_NODES) ? cnt[i] : 0;
    s[threadIdx.x] = v;
    __syncthreads();
    for (int off = 1; off < SCAN_BLK; off <<= 1) {
        int t = (threadIdx.x >= off) ? s[threadIdx.x - off] : 0;
        __syncthreads();
        s[threadIdx.x] += t;
        __syncthreads();
    }
    if (i < N_NODES) tmp[i] = s[threadIdx.x] - v;  // exclusive within block
    if (threadIdx.x == SCAN_BLK - 1) bsum[blockIdx.x] = s[threadIdx.x];
}

__global__ void scan2_kernel(int* __restrict__ bsum) {  // single block of 512
    __shared__ int s[512];
    int v = (threadIdx.x < NBLK) ? bsum[threadIdx.x] : 0;
    s[threadIdx.x] = v;
    __syncthreads();
    for (int off = 1; off < 512; off <<= 1) {
        int t = (threadIdx.x >= off) ? s[threadIdx.x - off] : 0;
        __syncthreads();
        s[threadIdx.x] += t;
        __syncthreads();
    }
    if (threadIdx.x < NBLK) bsum[threadIdx.x] = s[threadIdx.x] - v;  // exclusive
}

// ---- rowptr/cursor finalize + disq (fused) ----
__global__ void scan3_kernel(const int* __restrict__ tmp, const int* __restrict__ bsum,
                             const int* __restrict__ cnt, int* __restrict__ rowptr,
                             int* __restrict__ cursor, float* __restrict__ disq) {
    int i = blockIdx.x * blockDim.x + threadIdx.x;
    if (i < N_NODES) {
        int r = tmp[i] + bsum[i / SCAN_BLK];
        rowptr[i] = r;
        cursor[i] = r;
        disq[i] = rsqrtf(1.0f + (float)cnt[i]);
    }
    if (i == N_NODES) rowptr[N_NODES] = N_EDGES;
}

// ---- scatter edge src indices into CSR slots; 4 edges/thread ----
__global__ void fill_csr_kernel(const int* __restrict__ src, const int* __restrict__ dst,
                                int* __restrict__ cursor, int* __restrict__ csr_src) {
    int t = blockIdx.x * blockDim.x + threadIdx.x;
    if (t * 4 >= N_EDGES) return;
    const int4 s = *reinterpret_cast<const int4*>(src + t * 4);
    const int4 d = *reinterpret_cast<const int4*>(dst + t * 4);
    csr_src[atomicAdd(&cursor[d.x], 1)] = s.x;
    csr_src[atomicAdd(&cursor[d.y], 1)] = s.y;
    csr_src[atomicAdd(&cursor[d.z], 1)] = s.z;
    csr_src[atomicAdd(&cursor[d.w], 1)] = s.w;
}

// ---- h = x @ W ; W and x-rows staged in LDS ----
template <int D_IN, int D_OUT>
__global__ void linear_kernel(const float* __restrict__ x, const float* __restrict__ W,
                              float* __restrict__ h) {
    constexpr int NPB = 256 / D_OUT;  // nodes per block
    __shared__ float sW[D_IN * D_OUT];
    __shared__ float sx[NPB][D_IN];
    for (int i = threadIdx.x; i < D_IN * D_OUT; i += 256) sW[i] = W[i];
    int local = threadIdx.x / D_OUT;
    int col   = threadIdx.x % D_OUT;
    int node  = blockIdx.x * NPB + local;
    if (node < N_NODES) {
        for (int k = col; k < D_IN; k += D_OUT) sx[local][k] = x[(size_t)node * D_IN + k];
    }
    __syncthreads();
    if (node >= N_NODES) return;
    float acc = 0.f;
#pragma unroll
    for (int k = 0; k < D_IN; ++k) acc = fmaf(sx[local][k], sW[k * D_OUT + col], acc);
    h[(size_t)node * D_OUT + col] = acc;
}

// ---- gather-reduce + fused finish ----
// out = [relu]( disq[n] * ( sum_nbr disq[s]*h[s]  +  disq[n]*h[n] ) + b )
template <int D, bool RELU>
__global__ void gather_finish_kernel(const int* __restrict__ rowptr,
                                     const int* __restrict__ csr_src,
                                     const float* __restrict__ h,
                                     const float* __restrict__ disq,
                                     const float* __restrict__ b,
                                     float* __restrict__ out) {
    constexpr int TPN = D / 4;  // threads per node
    int t = blockIdx.x * blockDim.x + threadIdx.x;
    int node = t / TPN;
    if (node >= N_NODES) return;
    int part = t % TPN;
    int beg = rowptr[node];
    int end = rowptr[node + 1];
    float4 a0 = {0.f, 0.f, 0.f, 0.f};
    float4 a1 = {0.f, 0.f, 0.f, 0.f};
    int j = beg;
    for (; j + 1 < end; j += 2) {
        int s0 = csr_src[j];
        int s1 = csr_src[j + 1];
        float w0 = disq[s0];
        float w1 = disq[s1];
        const float4 v0 = *reinterpret_cast<const float4*>(h + (size_t)s0 * D + part * 4);
        const float4 v1 = *reinterpret_cast<const float4*>(h + (size_t)s1 * D + part * 4);
        a0.x = fmaf(v0.x, w0, a0.x); a1.x = fmaf(v1.x, w1, a1.x);
        a0.y = fmaf(v0.y, w0, a0.y); a1.y = fmaf(v1.y, w1, a1.y);
        a0.z = fmaf(v0.z, w0, a0.z); a1.z = fmaf(v1.z, w1, a1.z);
        a0.w = fmaf(v0.w, w0, a0.w); a1.w = fmaf(v1.w, w1, a1.w);
    }
    if (j < end) {
        int s0 = csr_src[j];
        float w0 = disq[s0];
        const float4 v0 = *reinterpret_cast<const float4*>(h + (size_t)s0 * D + part * 4);
        a0.x = fmaf(v0.x, w0, a0.x);
        a0.y = fmaf(v0.y, w0, a0.y);
        a0.z = fmaf(v0.z, w0, a0.z);
        a0.w = fmaf(v0.w, w0, a0.w);
    }
    float dn = disq[node];
    const float4 hv = *reinterpret_cast<const float4*>(h + (size_t)node * D + part * 4);
    const float4 bv = *reinterpret_cast<const float4*>(b + part * 4);
    float4 acc;
    acc.x = fmaf(a0.x + a1.x + dn * hv.x, dn, bv.x);
    acc.y = fmaf(a0.y + a1.y + dn * hv.y, dn, bv.y);
    acc.z = fmaf(a0.z + a1.z + dn * hv.z, dn, bv.z);
    acc.w = fmaf(a0.w + a1.w + dn * hv.w, dn, bv.w);
    if (RELU) {
        acc.x = (acc.x >= 0.f) ? acc.x : NEG * acc.x;
        acc.y = (acc.y >= 0.f) ? acc.y : NEG * acc.y;
        acc.z = (acc.z >= 0.f) ? acc.z : NEG * acc.z;
        acc.w = (acc.w >= 0.f) ? acc.w : NEG * acc.w;
    }
    *reinterpret_cast<float4*>(out + (size_t)node * D + part * 4) = acc;
}

extern "C" void kernel_launch(void* const* d_in, const int* in_sizes, int n_in,
                              void* d_out, int out_size, void* d_ws, size_t ws_size,
                              hipStream_t stream) {
    const float* x  = (const float*)d_in[0];
    const int* ei   = (const int*)d_in[1];
    const int* src  = ei;            // edge_index[0]
    const int* dst  = ei + N_EDGES;  // edge_index[1]
    const float* W1 = (const float*)d_in[2];
    const float* b1 = (const float*)d_in[3];
    const float* W2 = (const float*)d_in[4];
    const float* b2 = (const float*)d_in[5];
    const float* W3 = (const float*)d_in[6];
    const float* b3 = (const float*)d_in[7];

    float* out  = (float*)d_out;
    float* emb1 = out;                          // N x 64
    float* emb2 = out + (size_t)N_NODES * 64;   // N x 64
    float* emb3 = out + (size_t)N_NODES * 128;  // N x 32

    char* ws = (char*)d_ws;
    int*   cnt     = (int*)ws;    ws += sizeof(int)   * N_NODES;
    float* disq    = (float*)ws;  ws += sizeof(float) * N_NODES;
    int*   tmp     = (int*)ws;    ws += sizeof(int)   * N_NODES;
    int*   bsum    = (int*)ws;    ws += sizeof(int)   * 512;
    int*   rowptr  = (int*)ws;    ws += sizeof(int)   * (N_NODES + 1);
    int*   cursor  = (int*)ws;    ws += sizeof(int)   * N_NODES;
    int*   csr_src = (int*)ws;    ws += sizeof(int)   * N_EDGES;
    float* h       = (float*)ws;  ws += sizeof(float) * (size_t)N_NODES * 64;

    const int BLK = 256;
    const int gE4   = (N_EDGES / 4 + BLK - 1) / BLK;
    const int gN1   = (N_NODES + 1 + BLK - 1) / BLK;
    const int gN16  = (N_NODES * 16 + BLK - 1) / BLK;  // gather D=64
    const int gN8   = (N_NODES * 8  + BLK - 1) / BLK;  // gather D=32
    const int gLin64 = (N_NODES + 3) / 4;   // linear D_OUT=64: 4 nodes/block
    const int gLin32 = (N_NODES + 7) / 8;   // linear D_OUT=32: 8 nodes/block

    // ---- CSR build (once; reused by all 3 layers) ----
    hipMemsetAsync(cnt, 0, sizeof(int) * N_NODES, stream);
    count_kernel<<<gE4, BLK, 0, stream>>>(dst, cnt);
    scan1_kernel<<<NBLK, SCAN_BLK, 0, stream>>>(cnt, tmp, bsum);
    scan2_kernel<<<1, 512, 0, stream>>>(bsum);
    scan3_kernel<<<gN1, BLK, 0, stream>>>(tmp, bsum, cnt, rowptr, cursor, disq);
    fill_csr_kernel<<<gE4, BLK, 0, stream>>>(src, dst, cursor, csr_src);

    // ---- layer 1: x[64] -> emb1[64], leaky_relu ----
    linear_kernel<64, 64><<<gLin64, BLK, 0, stream>>>(x, W1, h);
    gather_finish_kernel<64, true><<<gN16, BLK, 0, stream>>>(rowptr, csr_src, h, disq, b1, emb1);

    // ---- layer 2: emb1[64] -> emb2[64], leaky_relu ----
    linear_kernel<64, 64><<<gLin64, BLK, 0, stream>>>(emb1, W2, h);
    gather_finish_kernel<64, true><<<gN16, BLK, 0, stream>>>(rowptr, csr_src, h, disq, b2, emb2);

    // ---- layer 3: emb2[64] -> emb3[32], no activation ----
    linear_kernel<64, 32><<<gLin32, BLK, 0, stream>>>(emb2, W3, h);
    gather_finish_kernel<32, false><<<gN8, BLK, 0, stream>>>(rowptr, csr_src, h, disq, b3, emb3);
}

// Round 4
// 496.913 us; speedup vs baseline: 7.5675x; 1.2901x over previous
//
#include <hip/hip_runtime.h>

// GCN_80376017977701: 3-layer GCN, N=100000, E=1600000, dims 64->64->64->32,
// symmetric norm with self-loops, leaky_relu(0.01) between layers.
// R4: binned CSR build — kills the 1.6M random global atomics of count/fill.
//   bucket = dst>>8 (256 nodes, 391 buckets):
//     bucket_count (LDS-aggregated) -> bucket_scan (1 block) ->
//     bin (two-pass, per-block LDS reservation, contiguous runs) ->
//     build_csr (per-bucket: LDS node-count + scan -> rowptr/disq/csr scatter
//                within an L1-resident 16KB window)
//   per layer: linear (LDS-staged) -> gather_finish (fused norm/bias/relu).

constexpr int N_NODES = 100000;
constexpr int N_EDGES = 1600000;
constexpr int E4 = N_EDGES / 4;          // 400000 int4 elements
constexpr float NEG = 0.01f;

constexpr int BSHIFT = 8;                 // 256 nodes per bucket
constexpr int BKT_NODES = 1 << BSHIFT;
constexpr int NBKT = (N_NODES + BKT_NODES - 1) >> BSHIFT;  // 391
constexpr int EPB = 4096;                 // edges per bin/count block
constexpr int ABLK = (N_EDGES + EPB - 1) / EPB;            // 391 blocks

// ---- A0: per-bucket edge counts (LDS-aggregated) ----
__global__ void bucket_count_kernel(const int* __restrict__ dst, int* __restrict__ bkt_cnt) {
    __shared__ int sc[NBKT];
    for (int i = threadIdx.x; i < NBKT; i += 256) sc[i] = 0;
    __syncthreads();
    for (int k = 0; k < 4; ++k) {
        int idx4 = blockIdx.x * 1024 + k * 256 + threadIdx.x;
        if (idx4 < E4) {
            const int4 d = *reinterpret_cast<const int4*>(dst + idx4 * 4);
            atomicAdd(&sc[d.x >> BSHIFT], 1);
            atomicAdd(&sc[d.y >> BSHIFT], 1);
            atomicAdd(&sc[d.z >> BSHIFT], 1);
            atomicAdd(&sc[d.w >> BSHIFT], 1);
        }
    }
    __syncthreads();
    for (int i = threadIdx.x; i < NBKT; i += 256) {
        int c = sc[i];
        if (c) atomicAdd(&bkt_cnt[i], c);
    }
}

// ---- exclusive scan over NBKT bucket counts (single block of 512) ----
__global__ void bucket_scan_kernel(const int* __restrict__ bkt_cnt,
                                   int* __restrict__ bkt_base, int* __restrict__ bkt_cursor) {
    __shared__ int s[512];
    int v = (threadIdx.x < NBKT) ? bkt_cnt[threadIdx.x] : 0;
    s[threadIdx.x] = v;
    __syncthreads();
    for (int off = 1; off < 512; off <<= 1) {
        int t = (threadIdx.x >= off) ? s[threadIdx.x - off] : 0;
        __syncthreads();
        s[threadIdx.x] += t;
        __syncthreads();
    }
    if (threadIdx.x < NBKT) {
        int b = s[threadIdx.x] - v;      // exclusive
        bkt_base[threadIdx.x] = b;
        bkt_cursor[threadIdx.x] = b;
    }
    if (threadIdx.x == NBKT) bkt_base[NBKT] = N_EDGES;
}

// ---- A1: bin edges into bucket-grouped (src,dst) pair storage ----
__global__ void bin_kernel(const int* __restrict__ src, const int* __restrict__ dst,
                           int* __restrict__ bkt_cursor, int2* __restrict__ pairs) {
    __shared__ int scnt[NBKT];
    __shared__ int sbase[NBKT];
    __shared__ int soff[NBKT];
    for (int i = threadIdx.x; i < NBKT; i += 256) { scnt[i] = 0; soff[i] = 0; }
    __syncthreads();
    // pass 1: count this block's edges per bucket
    for (int k = 0; k < 4; ++k) {
        int idx4 = blockIdx.x * 1024 + k * 256 + threadIdx.x;
        if (idx4 < E4) {
            const int4 d = *reinterpret_cast<const int4*>(dst + idx4 * 4);
            atomicAdd(&scnt[d.x >> BSHIFT], 1);
            atomicAdd(&scnt[d.y >> BSHIFT], 1);
            atomicAdd(&scnt[d.z >> BSHIFT], 1);
            atomicAdd(&scnt[d.w >> BSHIFT], 1);
        }
    }
    __syncthreads();
    // reserve contiguous runs per bucket
    for (int i = threadIdx.x; i < NBKT; i += 256) {
        int c = scnt[i];
        if (c) sbase[i] = atomicAdd(&bkt_cursor[i], c);
    }
    __syncthreads();
    // pass 2: emit
    for (int k = 0; k < 4; ++k) {
        int idx4 = blockIdx.x * 1024 + k * 256 + threadIdx.x;
        if (idx4 < E4) {
            const int4 s = *reinterpret_cast<const int4*>(src + idx4 * 4);
            const int4 d = *reinterpret_cast<const int4*>(dst + idx4 * 4);
            int b, pos;
            b = d.x >> BSHIFT; pos = sbase[b] + atomicAdd(&soff[b], 1); pairs[pos] = make_int2(s.x, d.x);
            b = d.y >> BSHIFT; pos = sbase[b] + atomicAdd(&soff[b], 1); pairs[pos] = make_int2(s.y, d.y);
            b = d.z >> BSHIFT; pos = sbase[b] + atomicAdd(&soff[b], 1); pairs[pos] = make_int2(s.z, d.z);
            b = d.w >> BSHIFT; pos = sbase[b] + atomicAdd(&soff[b], 1); pairs[pos] = make_int2(s.w, d.w);
        }
    }
}

// ---- B: per-bucket node counts (LDS), scan, rowptr/disq write, csr scatter ----
__global__ void build_csr_kernel(const int2* __restrict__ pairs,
                                 const int* __restrict__ bkt_base,
                                 int* __restrict__ rowptr, float* __restrict__ disq,
                                 int* __restrict__ csr_src) {
    __shared__ int scnt[BKT_NODES];
    __shared__ int ssc[BKT_NODES];
    __shared__ int scur[BKT_NODES];
    const int b = blockIdx.x;
    const int n0 = b << BSHIFT;
    const int nb = min(BKT_NODES, N_NODES - n0);
    const int beg = bkt_base[b];
    const int end = bkt_base[b + 1];
    scnt[threadIdx.x] = 0;
    __syncthreads();
    // count per node
    for (int j = beg + threadIdx.x; j < end; j += 256) {
        atomicAdd(&scnt[pairs[j].y - n0], 1);
    }
    __syncthreads();
    // exclusive scan of 256 counts
    int v = scnt[threadIdx.x];
    ssc[threadIdx.x] = v;
    __syncthreads();
    for (int off = 1; off < 256; off <<= 1) {
        int t = (threadIdx.x >= off) ? ssc[threadIdx.x - off] : 0;
        __syncthreads();
        ssc[threadIdx.x] += t;
        __syncthreads();
    }
    int excl = ssc[threadIdx.x] - v;
    scur[threadIdx.x] = beg + excl;
    if (threadIdx.x < nb) {
        rowptr[n0 + threadIdx.x] = beg + excl;
        disq[n0 + threadIdx.x] = rsqrtf(1.0f + (float)v);
    }
    if (b == NBKT - 1 && threadIdx.x == 0) rowptr[N_NODES] = N_EDGES;
    __syncthreads();
    // scatter src indices into the bucket's csr window (L1/L2-resident)
    for (int j = beg + threadIdx.x; j < end; j += 256) {
        int2 p = pairs[j];
        int pos = atomicAdd(&scur[p.y - n0], 1);
        csr_src[pos] = p.x;
    }
}

// ---- h = x @ W ; W and x-rows staged in LDS ----
template <int D_IN, int D_OUT>
__global__ void linear_kernel(const float* __restrict__ x, const float* __restrict__ W,
                              float* __restrict__ h) {
    constexpr int NPB = 256 / D_OUT;  // nodes per block
    __shared__ float sW[D_IN * D_OUT];
    __shared__ float sx[NPB][D_IN];
    for (int i = threadIdx.x; i < D_IN * D_OUT; i += 256) sW[i] = W[i];
    int local = threadIdx.x / D_OUT;
    int col   = threadIdx.x % D_OUT;
    int node  = blockIdx.x * NPB + local;
    if (node < N_NODES) {
        for (int k = col; k < D_IN; k += D_OUT) sx[local][k] = x[(size_t)node * D_IN + k];
    }
    __syncthreads();
    if (node >= N_NODES) return;
    float acc = 0.f;
#pragma unroll
    for (int k = 0; k < D_IN; ++k) acc = fmaf(sx[local][k], sW[k * D_OUT + col], acc);
    h[(size_t)node * D_OUT + col] = acc;
}

// ---- gather-reduce + fused finish ----
// out = [relu]( disq[n] * ( sum_nbr disq[s]*h[s]  +  disq[n]*h[n] ) + b )
template <int D, bool RELU>
__global__ void gather_finish_kernel(const int* __restrict__ rowptr,
                                     const int* __restrict__ csr_src,
                                     const float* __restrict__ h,
                                     const float* __restrict__ disq,
                                     const float* __restrict__ b,
                                     float* __restrict__ out) {
    constexpr int TPN = D / 4;  // threads per node
    int t = blockIdx.x * blockDim.x + threadIdx.x;
    int node = t / TPN;
    if (node >= N_NODES) return;
    int part = t % TPN;
    int beg = rowptr[node];
    int end = rowptr[node + 1];
    float4 a0 = {0.f, 0.f, 0.f, 0.f};
    float4 a1 = {0.f, 0.f, 0.f, 0.f};
    int j = beg;
    for (; j + 1 < end; j += 2) {
        int s0 = csr_src[j];
        int s1 = csr_src[j + 1];
        float w0 = disq[s0];
        float w1 = disq[s1];
        const float4 v0 = *reinterpret_cast<const float4*>(h + (size_t)s0 * D + part * 4);
        const float4 v1 = *reinterpret_cast<const float4*>(h + (size_t)s1 * D + part * 4);
        a0.x = fmaf(v0.x, w0, a0.x); a1.x = fmaf(v1.x, w1, a1.x);
        a0.y = fmaf(v0.y, w0, a0.y); a1.y = fmaf(v1.y, w1, a1.y);
        a0.z = fmaf(v0.z, w0, a0.z); a1.z = fmaf(v1.z, w1, a1.z);
        a0.w = fmaf(v0.w, w0, a0.w); a1.w = fmaf(v1.w, w1, a1.w);
    }
    if (j < end) {
        int s0 = csr_src[j];
        float w0 = disq[s0];
        const float4 v0 = *reinterpret_cast<const float4*>(h + (size_t)s0 * D + part * 4);
        a0.x = fmaf(v0.x, w0, a0.x);
        a0.y = fmaf(v0.y, w0, a0.y);
        a0.z = fmaf(v0.z, w0, a0.z);
        a0.w = fmaf(v0.w, w0, a0.w);
    }
    float dn = disq[node];
    const float4 hv = *reinterpret_cast<const float4*>(h + (size_t)node * D + part * 4);
    const float4 bv = *reinterpret_cast<const float4*>(b + part * 4);
    float4 acc;
    acc.x = fmaf(a0.x + a1.x + dn * hv.x, dn, bv.x);
    acc.y = fmaf(a0.y + a1.y + dn * hv.y, dn, bv.y);
    acc.z = fmaf(a0.z + a1.z + dn * hv.z, dn, bv.z);
    acc.w = fmaf(a0.w + a1.w + dn * hv.w, dn, bv.w);
    if (RELU) {
        acc.x = (acc.x >= 0.f) ? acc.x : NEG * acc.x;
        acc.y = (acc.y >= 0.f) ? acc.y : NEG * acc.y;
        acc.z = (acc.z >= 0.f) ? acc.z : NEG * acc.z;
        acc.w = (acc.w >= 0.f) ? acc.w : NEG * acc.w;
    }
    *reinterpret_cast<float4*>(out + (size_t)node * D + part * 4) = acc;
}

extern "C" void kernel_launch(void* const* d_in, const int* in_sizes, int n_in,
                              void* d_out, int out_size, void* d_ws, size_t ws_size,
                              hipStream_t stream) {
    const float* x  = (const float*)d_in[0];
    const int* ei   = (const int*)d_in[1];
    const int* src  = ei;            // edge_index[0]
    const int* dst  = ei + N_EDGES;  // edge_index[1]
    const float* W1 = (const float*)d_in[2];
    const float* b1 = (const float*)d_in[3];
    const float* W2 = (const float*)d_in[4];
    const float* b2 = (const float*)d_in[5];
    const float* W3 = (const float*)d_in[6];
    const float* b3 = (const float*)d_in[7];

    float* out  = (float*)d_out;
    float* emb1 = out;                          // N x 64
    float* emb2 = out + (size_t)N_NODES * 64;   // N x 64
    float* emb3 = out + (size_t)N_NODES * 128;  // N x 32

    char* ws = (char*)d_ws;
    int*   bkt_cnt    = (int*)ws;   ws += sizeof(int) * (NBKT + 1);
    int*   bkt_base   = (int*)ws;   ws += sizeof(int) * (NBKT + 1);
    int*   bkt_cursor = (int*)ws;   ws += sizeof(int) * (NBKT + 1);
    float* disq       = (float*)ws; ws += sizeof(float) * N_NODES;
    int*   rowptr     = (int*)ws;   ws += sizeof(int) * (N_NODES + 1);
    int2*  pairs      = (int2*)ws;  ws += sizeof(int2) * N_EDGES;
    int*   csr_src    = (int*)ws;   ws += sizeof(int) * N_EDGES;
    float* h          = (float*)ws; ws += sizeof(float) * (size_t)N_NODES * 64;

    const int BLK = 256;
    const int gN16  = (N_NODES * 16 + BLK - 1) / BLK;  // gather D=64
    const int gN8   = (N_NODES * 8  + BLK - 1) / BLK;  // gather D=32
    const int gLin64 = (N_NODES + 3) / 4;   // linear D_OUT=64: 4 nodes/block
    const int gLin32 = (N_NODES + 7) / 8;   // linear D_OUT=32: 8 nodes/block

    // ---- CSR build (once; reused by all 3 layers) ----
    hipMemsetAsync(bkt_cnt, 0, sizeof(int) * (NBKT + 1), stream);
    bucket_count_kernel<<<ABLK, BLK, 0, stream>>>(dst, bkt_cnt);
    bucket_scan_kernel<<<1, 512, 0, stream>>>(bkt_cnt, bkt_base, bkt_cursor);
    bin_kernel<<<ABLK, BLK, 0, stream>>>(src, dst, bkt_cursor, pairs);
    build_csr_kernel<<<NBKT, BLK, 0, stream>>>(pairs, bkt_base, rowptr, disq, csr_src);

    // ---- layer 1: x[64] -> emb1[64], leaky_relu ----
    linear_kernel<64, 64><<<gLin64, BLK, 0, stream>>>(x, W1, h);
    gather_finish_kernel<64, true><<<gN16, BLK, 0, stream>>>(rowptr, csr_src, h, disq, b1, emb1);

    // ---- layer 2: emb1[64] -> emb2[64], leaky_relu ----
    linear_kernel<64, 64><<<gLin64, BLK, 0, stream>>>(emb1, W2, h);
    gather_finish_kernel<64, true><<<gN16, BLK, 0, stream>>>(rowptr, csr_src, h, disq, b2, emb2);

    // ---- layer 3: emb2[64] -> emb3[32], no activation ----
    linear_kernel<64, 32><<<gLin32, BLK, 0, stream>>>(emb2, W3, h);
    gather_finish_kernel<32, false><<<gN8, BLK, 0, stream>>>(rowptr, csr_src, h, disq, b3, emb3);
}

// Round 5
// 395.882 us; speedup vs baseline: 9.4987x; 1.2552x over previous
//
#include <hip/hip_runtime.h>

// GCN_80376017977701: 3-layer GCN, N=100000, E=1600000, dims 64->64->64->32,
// symmetric norm with self-loops, leaky_relu(0.01) between layers.
// R5: gather is L2-miss bound (FETCH 282MB vs 410MB logical, h=25.6MB >> 4MB L2).
//   (a) h stored as bf16 (12.8MB) -> halves gather bytes + footprint
//   (b) per-dst-bucket counting sort of adjacency by src-bucket -> concurrent
//       gather blocks sweep src space as a coherent front -> L2 reuse
// CSR build: bucket_count -> bucket_scan -> bin -> sort_pairs -> build_csr.

constexpr int N_NODES = 100000;
constexpr int N_EDGES = 1600000;
constexpr int E4 = N_EDGES / 4;          // 400000 int4 elements
constexpr float NEG = 0.01f;

constexpr int BSHIFT = 8;                 // 256 nodes per bucket
constexpr int BKT_NODES = 1 << BSHIFT;
constexpr int NBKT = (N_NODES + BKT_NODES - 1) >> BSHIFT;  // 391
constexpr int EPB = 4096;                 // edges per bin/count block
constexpr int ABLK = (N_EDGES + EPB - 1) / EPB;            // 391 blocks

// ---- bf16 helpers (manual, no header dependency) ----
__device__ __forceinline__ unsigned short f2bf(float f) {
    unsigned u = __float_as_uint(f);
    unsigned r = (u + 0x7fffu + ((u >> 16) & 1u)) >> 16;  // round-nearest-even
    return (unsigned short)r;
}
__device__ __forceinline__ float bf2f(unsigned short us) {
    return __uint_as_float(((unsigned)us) << 16);
}

// ---- A0: per-bucket edge counts (LDS-aggregated) ----
__global__ void bucket_count_kernel(const int* __restrict__ dst, int* __restrict__ bkt_cnt) {
    __shared__ int sc[NBKT];
    for (int i = threadIdx.x; i < NBKT; i += 256) sc[i] = 0;
    __syncthreads();
    for (int k = 0; k < 4; ++k) {
        int idx4 = blockIdx.x * 1024 + k * 256 + threadIdx.x;
        if (idx4 < E4) {
            const int4 d = *reinterpret_cast<const int4*>(dst + idx4 * 4);
            atomicAdd(&sc[d.x >> BSHIFT], 1);
            atomicAdd(&sc[d.y >> BSHIFT], 1);
            atomicAdd(&sc[d.z >> BSHIFT], 1);
            atomicAdd(&sc[d.w >> BSHIFT], 1);
        }
    }
    __syncthreads();
    for (int i = threadIdx.x; i < NBKT; i += 256) {
        int c = sc[i];
        if (c) atomicAdd(&bkt_cnt[i], c);
    }
}

// ---- exclusive scan over NBKT bucket counts (single block of 512) ----
__global__ void bucket_scan_kernel(const int* __restrict__ bkt_cnt,
                                   int* __restrict__ bkt_base, int* __restrict__ bkt_cursor) {
    __shared__ int s[512];
    int v = (threadIdx.x < NBKT) ? bkt_cnt[threadIdx.x] : 0;
    s[threadIdx.x] = v;
    __syncthreads();
    for (int off = 1; off < 512; off <<= 1) {
        int t = (threadIdx.x >= off) ? s[threadIdx.x - off] : 0;
        __syncthreads();
        s[threadIdx.x] += t;
        __syncthreads();
    }
    if (threadIdx.x < NBKT) {
        int b = s[threadIdx.x] - v;      // exclusive
        bkt_base[threadIdx.x] = b;
        bkt_cursor[threadIdx.x] = b;
    }
    if (threadIdx.x == NBKT) bkt_base[NBKT] = N_EDGES;
}

// ---- A1: bin edges into bucket-grouped (src,dst) pair storage ----
__global__ void bin_kernel(const int* __restrict__ src, const int* __restrict__ dst,
                           int* __restrict__ bkt_cursor, int2* __restrict__ pairs) {
    __shared__ int scnt[NBKT];
    __shared__ int sbase[NBKT];
    __shared__ int soff[NBKT];
    for (int i = threadIdx.x; i < NBKT; i += 256) { scnt[i] = 0; soff[i] = 0; }
    __syncthreads();
    for (int k = 0; k < 4; ++k) {
        int idx4 = blockIdx.x * 1024 + k * 256 + threadIdx.x;
        if (idx4 < E4) {
            const int4 d = *reinterpret_cast<const int4*>(dst + idx4 * 4);
            atomicAdd(&scnt[d.x >> BSHIFT], 1);
            atomicAdd(&scnt[d.y >> BSHIFT], 1);
            atomicAdd(&scnt[d.z >> BSHIFT], 1);
            atomicAdd(&scnt[d.w >> BSHIFT], 1);
        }
    }
    __syncthreads();
    for (int i = threadIdx.x; i < NBKT; i += 256) {
        int c = scnt[i];
        if (c) sbase[i] = atomicAdd(&bkt_cursor[i], c);
    }
    __syncthreads();
    for (int k = 0; k < 4; ++k) {
        int idx4 = blockIdx.x * 1024 + k * 256 + threadIdx.x;
        if (idx4 < E4) {
            const int4 s = *reinterpret_cast<const int4*>(src + idx4 * 4);
            const int4 d = *reinterpret_cast<const int4*>(dst + idx4 * 4);
            int b, pos;
            b = d.x >> BSHIFT; pos = sbase[b] + atomicAdd(&soff[b], 1); pairs[pos] = make_int2(s.x, d.x);
            b = d.y >> BSHIFT; pos = sbase[b] + atomicAdd(&soff[b], 1); pairs[pos] = make_int2(s.y, d.y);
            b = d.z >> BSHIFT; pos = sbase[b] + atomicAdd(&soff[b], 1); pairs[pos] = make_int2(s.z, d.z);
            b = d.w >> BSHIFT; pos = sbase[b] + atomicAdd(&soff[b], 1); pairs[pos] = make_int2(s.w, d.w);
        }
    }
}

// ---- A2: counting-sort each dst-bucket's pairs by src-bucket (locality) ----
__global__ void sort_pairs_kernel(const int2* __restrict__ pairs,
                                  const int* __restrict__ bkt_base,
                                  int2* __restrict__ pairs2) {
    __shared__ int s[512];
    __shared__ int sbase[NBKT];
    __shared__ int soff[NBKT];
    const int b = blockIdx.x;
    const int beg = bkt_base[b];
    const int end = bkt_base[b + 1];
    s[threadIdx.x] = 0;
    if (threadIdx.x < NBKT) soff[threadIdx.x] = 0;
    __syncthreads();
    for (int j = beg + threadIdx.x; j < end; j += 512) {
        atomicAdd(&s[pairs[j].x >> BSHIFT], 1);
    }
    __syncthreads();
    int v = s[threadIdx.x];
    __syncthreads();
    // Hillis-Steele inclusive scan over 512
    for (int off = 1; off < 512; off <<= 1) {
        int t = (threadIdx.x >= off) ? s[threadIdx.x - off] : 0;
        __syncthreads();
        s[threadIdx.x] += t;
        __syncthreads();
    }
    if (threadIdx.x < NBKT) sbase[threadIdx.x] = s[threadIdx.x] - v;  // exclusive
    __syncthreads();
    for (int j = beg + threadIdx.x; j < end; j += 512) {
        int2 p = pairs[j];
        int sb = p.x >> BSHIFT;
        int pos = beg + sbase[sb] + atomicAdd(&soff[sb], 1);
        pairs2[pos] = p;
    }
}

// ---- B: per-bucket node counts (LDS), scan, rowptr/disq write, csr scatter ----
__global__ void build_csr_kernel(const int2* __restrict__ pairs,
                                 const int* __restrict__ bkt_base,
                                 int* __restrict__ rowptr, float* __restrict__ disq,
                                 int* __restrict__ csr_src) {
    __shared__ int scnt[BKT_NODES];
    __shared__ int ssc[BKT_NODES];
    __shared__ int scur[BKT_NODES];
    const int b = blockIdx.x;
    const int n0 = b << BSHIFT;
    const int nb = min(BKT_NODES, N_NODES - n0);
    const int beg = bkt_base[b];
    const int end = bkt_base[b + 1];
    scnt[threadIdx.x] = 0;
    __syncthreads();
    for (int j = beg + threadIdx.x; j < end; j += 256) {
        atomicAdd(&scnt[pairs[j].y - n0], 1);
    }
    __syncthreads();
    int v = scnt[threadIdx.x];
    ssc[threadIdx.x] = v;
    __syncthreads();
    for (int off = 1; off < 256; off <<= 1) {
        int t = (threadIdx.x >= off) ? ssc[threadIdx.x - off] : 0;
        __syncthreads();
        ssc[threadIdx.x] += t;
        __syncthreads();
    }
    int excl = ssc[threadIdx.x] - v;
    scur[threadIdx.x] = beg + excl;
    if (threadIdx.x < nb) {
        rowptr[n0 + threadIdx.x] = beg + excl;
        disq[n0 + threadIdx.x] = rsqrtf(1.0f + (float)v);
    }
    if (b == NBKT - 1 && threadIdx.x == 0) rowptr[N_NODES] = N_EDGES;
    __syncthreads();
    // scatter src indices (sorted pairs -> per-row lists approx. src-sorted)
    for (int j = beg + threadIdx.x; j < end; j += 256) {
        int2 p = pairs[j];
        int pos = atomicAdd(&scur[p.y - n0], 1);
        csr_src[pos] = p.x;
    }
}

// ---- h = x @ W -> bf16 ; W and x-rows staged in LDS ----
template <int D_IN, int D_OUT>
__global__ void linear_kernel(const float* __restrict__ x, const float* __restrict__ W,
                              unsigned short* __restrict__ h) {
    constexpr int NPB = 256 / D_OUT;  // nodes per block
    __shared__ float sW[D_IN * D_OUT];
    __shared__ float sx[NPB][D_IN];
    for (int i = threadIdx.x; i < D_IN * D_OUT; i += 256) sW[i] = W[i];
    int local = threadIdx.x / D_OUT;
    int col   = threadIdx.x % D_OUT;
    int node  = blockIdx.x * NPB + local;
    if (node < N_NODES) {
        for (int k = col; k < D_IN; k += D_OUT) sx[local][k] = x[(size_t)node * D_IN + k];
    }
    __syncthreads();
    if (node >= N_NODES) return;
    float acc = 0.f;
#pragma unroll
    for (int k = 0; k < D_IN; ++k) acc = fmaf(sx[local][k], sW[k * D_OUT + col], acc);
    h[(size_t)node * D_OUT + col] = f2bf(acc);
}

// ---- gather-reduce + fused finish (bf16 h) ----
// out = [relu]( disq[n] * ( sum_nbr disq[s]*h[s]  +  disq[n]*h[n] ) + b )
template <int D, bool RELU>
__global__ void gather_finish_kernel(const int* __restrict__ rowptr,
                                     const int* __restrict__ csr_src,
                                     const unsigned short* __restrict__ h,
                                     const float* __restrict__ disq,
                                     const float* __restrict__ b,
                                     float* __restrict__ out) {
    constexpr int TPN = D / 4;  // threads per node (4 cols each)
    int t = blockIdx.x * blockDim.x + threadIdx.x;
    int node = t / TPN;
    if (node >= N_NODES) return;
    int part = t % TPN;
    int beg = rowptr[node];
    int end = rowptr[node + 1];
    float4 a0 = {0.f, 0.f, 0.f, 0.f};
    float4 a1 = {0.f, 0.f, 0.f, 0.f};
    int j = beg;
    for (; j + 1 < end; j += 2) {
        int s0 = csr_src[j];
        int s1 = csr_src[j + 1];
        float w0 = disq[s0];
        float w1 = disq[s1];
        const ushort4 u0 = *reinterpret_cast<const ushort4*>(h + (size_t)s0 * D + part * 4);
        const ushort4 u1 = *reinterpret_cast<const ushort4*>(h + (size_t)s1 * D + part * 4);
        a0.x = fmaf(bf2f(u0.x), w0, a0.x); a1.x = fmaf(bf2f(u1.x), w1, a1.x);
        a0.y = fmaf(bf2f(u0.y), w0, a0.y); a1.y = fmaf(bf2f(u1.y), w1, a1.y);
        a0.z = fmaf(bf2f(u0.z), w0, a0.z); a1.z = fmaf(bf2f(u1.z), w1, a1.z);
        a0.w = fmaf(bf2f(u0.w), w0, a0.w); a1.w = fmaf(bf2f(u1.w), w1, a1.w);
    }
    if (j < end) {
        int s0 = csr_src[j];
        float w0 = disq[s0];
        const ushort4 u0 = *reinterpret_cast<const ushort4*>(h + (size_t)s0 * D + part * 4);
        a0.x = fmaf(bf2f(u0.x), w0, a0.x);
        a0.y = fmaf(bf2f(u0.y), w0, a0.y);
        a0.z = fmaf(bf2f(u0.z), w0, a0.z);
        a0.w = fmaf(bf2f(u0.w), w0, a0.w);
    }
    float dn = disq[node];
    const ushort4 hu = *reinterpret_cast<const ushort4*>(h + (size_t)node * D + part * 4);
    const float4 bv = *reinterpret_cast<const float4*>(b + part * 4);
    float4 acc;
    acc.x = fmaf(a0.x + a1.x + dn * bf2f(hu.x), dn, bv.x);
    acc.y = fmaf(a0.y + a1.y + dn * bf2f(hu.y), dn, bv.y);
    acc.z = fmaf(a0.z + a1.z + dn * bf2f(hu.z), dn, bv.z);
    acc.w = fmaf(a0.w + a1.w + dn * bf2f(hu.w), dn, bv.w);
    if (RELU) {
        acc.x = (acc.x >= 0.f) ? acc.x : NEG * acc.x;
        acc.y = (acc.y >= 0.f) ? acc.y : NEG * acc.y;
        acc.z = (acc.z >= 0.f) ? acc.z : NEG * acc.z;
        acc.w = (acc.w >= 0.f) ? acc.w : NEG * acc.w;
    }
    *reinterpret_cast<float4*>(out + (size_t)node * D + part * 4) = acc;
}

extern "C" void kernel_launch(void* const* d_in, const int* in_sizes, int n_in,
                              void* d_out, int out_size, void* d_ws, size_t ws_size,
                              hipStream_t stream) {
    const float* x  = (const float*)d_in[0];
    const int* ei   = (const int*)d_in[1];
    const int* src  = ei;            // edge_index[0]
    const int* dst  = ei + N_EDGES;  // edge_index[1]
    const float* W1 = (const float*)d_in[2];
    const float* b1 = (const float*)d_in[3];
    const float* W2 = (const float*)d_in[4];
    const float* b2 = (const float*)d_in[5];
    const float* W3 = (const float*)d_in[6];
    const float* b3 = (const float*)d_in[7];

    float* out  = (float*)d_out;
    float* emb1 = out;                          // N x 64
    float* emb2 = out + (size_t)N_NODES * 64;   // N x 64
    float* emb3 = out + (size_t)N_NODES * 128;  // N x 32

    char* ws = (char*)d_ws;
    int*   bkt_cnt    = (int*)ws;   ws += sizeof(int) * (NBKT + 1);
    int*   bkt_base   = (int*)ws;   ws += sizeof(int) * (NBKT + 1);
    int*   bkt_cursor = (int*)ws;   ws += sizeof(int) * (NBKT + 1);
    ws = (char*)(((size_t)ws + 255) & ~(size_t)255);
    float* disq       = (float*)ws; ws += sizeof(float) * N_NODES;
    int*   rowptr     = (int*)ws;   ws += sizeof(int) * (N_NODES + 1);
    ws = (char*)(((size_t)ws + 255) & ~(size_t)255);
    int2*  pairs      = (int2*)ws;  ws += sizeof(int2) * N_EDGES;
    int2*  pairs2     = (int2*)ws;  ws += sizeof(int2) * N_EDGES;
    int*   csr_src    = (int*)ws;   ws += sizeof(int) * N_EDGES;
    unsigned short* h = (unsigned short*)ws; ws += sizeof(unsigned short) * (size_t)N_NODES * 64;

    const int BLK = 256;
    const int gN16  = (N_NODES * 16 + BLK - 1) / BLK;  // gather D=64
    const int gN8   = (N_NODES * 8  + BLK - 1) / BLK;  // gather D=32
    const int gLin64 = (N_NODES + 3) / 4;   // linear D_OUT=64: 4 nodes/block
    const int gLin32 = (N_NODES + 7) / 8;   // linear D_OUT=32: 8 nodes/block

    // ---- CSR build (once; reused by all 3 layers) ----
    hipMemsetAsync(bkt_cnt, 0, sizeof(int) * (NBKT + 1), stream);
    bucket_count_kernel<<<ABLK, BLK, 0, stream>>>(dst, bkt_cnt);
    bucket_scan_kernel<<<1, 512, 0, stream>>>(bkt_cnt, bkt_base, bkt_cursor);
    bin_kernel<<<ABLK, BLK, 0, stream>>>(src, dst, bkt_cursor, pairs);
    sort_pairs_kernel<<<NBKT, 512, 0, stream>>>(pairs, bkt_base, pairs2);
    build_csr_kernel<<<NBKT, BLK, 0, stream>>>(pairs2, bkt_base, rowptr, disq, csr_src);

    // ---- layer 1: x[64] -> emb1[64], leaky_relu ----
    linear_kernel<64, 64><<<gLin64, BLK, 0, stream>>>(x, W1, h);
    gather_finish_kernel<64, true><<<gN16, BLK, 0, stream>>>(rowptr, csr_src, h, disq, b1, emb1);

    // ---- layer 2: emb1[64] -> emb2[64], leaky_relu ----
    linear_kernel<64, 64><<<gLin64, BLK, 0, stream>>>(emb1, W2, h);
    gather_finish_kernel<64, true><<<gN16, BLK, 0, stream>>>(rowptr, csr_src, h, disq, b2, emb2);

    // ---- layer 3: emb2[64] -> emb3[32], no activation ----
    linear_kernel<64, 32><<<gLin32, BLK, 0, stream>>>(emb2, W3, h);
    gather_finish_kernel<32, false><<<gN8, BLK, 0, stream>>>(rowptr, csr_src, h, disq, b3, emb3);
}

// Round 6
// 302.468 us; speedup vs baseline: 12.4323x; 1.3088x over previous
//
#include <hip/hip_runtime.h>

// GCN_80376017977701: 3-layer GCN, N=100000, E=1600000, dims 64->64->64->32,
// symmetric norm with self-loops, leaky_relu(0.01) between layers.
// R6: linears via MFMA (16x16x32 bf16) with hi/lo bf16 split of BOTH input and
// W -> fp32-accurate linear at trivial MFMA cost; kills the LDS-read-bound
// scalar matmul (3x ~60us -> ~5us each). CSR build + bf16 gather unchanged.

constexpr int N_NODES = 100000;
constexpr int N_EDGES = 1600000;
constexpr int E4 = N_EDGES / 4;          // 400000 int4 elements
constexpr float NEG = 0.01f;

constexpr int BSHIFT = 8;                 // 256 nodes per bucket
constexpr int BKT_NODES = 1 << BSHIFT;
constexpr int NBKT = (N_NODES + BKT_NODES - 1) >> BSHIFT;  // 391
constexpr int EPB = 4096;                 // edges per bin/count block
constexpr int ABLK = (N_EDGES + EPB - 1) / EPB;            // 391 blocks

constexpr int NTILES = N_NODES / 16;      // 6250 (exact)

using short8 = __attribute__((ext_vector_type(8))) short;
using float4v = __attribute__((ext_vector_type(4))) float;

// ---- bf16 helpers ----
__device__ __forceinline__ unsigned short f2bf(float f) {
    unsigned u = __float_as_uint(f);
    unsigned r = (u + 0x7fffu + ((u >> 16) & 1u)) >> 16;  // round-nearest-even
    return (unsigned short)r;
}
__device__ __forceinline__ float bf2f(unsigned short us) {
    return __uint_as_float(((unsigned)us) << 16);
}

// ---- A0: per-bucket edge counts (LDS-aggregated) ----
__global__ void bucket_count_kernel(const int* __restrict__ dst, int* __restrict__ bkt_cnt) {
    __shared__ int sc[NBKT];
    for (int i = threadIdx.x; i < NBKT; i += 256) sc[i] = 0;
    __syncthreads();
    for (int k = 0; k < 4; ++k) {
        int idx4 = blockIdx.x * 1024 + k * 256 + threadIdx.x;
        if (idx4 < E4) {
            const int4 d = *reinterpret_cast<const int4*>(dst + idx4 * 4);
            atomicAdd(&sc[d.x >> BSHIFT], 1);
            atomicAdd(&sc[d.y >> BSHIFT], 1);
            atomicAdd(&sc[d.z >> BSHIFT], 1);
            atomicAdd(&sc[d.w >> BSHIFT], 1);
        }
    }
    __syncthreads();
    for (int i = threadIdx.x; i < NBKT; i += 256) {
        int c = sc[i];
        if (c) atomicAdd(&bkt_cnt[i], c);
    }
}

// ---- exclusive scan over NBKT bucket counts (single block of 512) ----
__global__ void bucket_scan_kernel(const int* __restrict__ bkt_cnt,
                                   int* __restrict__ bkt_base, int* __restrict__ bkt_cursor) {
    __shared__ int s[512];
    int v = (threadIdx.x < NBKT) ? bkt_cnt[threadIdx.x] : 0;
    s[threadIdx.x] = v;
    __syncthreads();
    for (int off = 1; off < 512; off <<= 1) {
        int t = (threadIdx.x >= off) ? s[threadIdx.x - off] : 0;
        __syncthreads();
        s[threadIdx.x] += t;
        __syncthreads();
    }
    if (threadIdx.x < NBKT) {
        int b = s[threadIdx.x] - v;      // exclusive
        bkt_base[threadIdx.x] = b;
        bkt_cursor[threadIdx.x] = b;
    }
    if (threadIdx.x == NBKT) bkt_base[NBKT] = N_EDGES;
}

// ---- A1: bin edges into bucket-grouped (src,dst) pair storage ----
__global__ void bin_kernel(const int* __restrict__ src, const int* __restrict__ dst,
                           int* __restrict__ bkt_cursor, int2* __restrict__ pairs) {
    __shared__ int scnt[NBKT];
    __shared__ int sbase[NBKT];
    __shared__ int soff[NBKT];
    for (int i = threadIdx.x; i < NBKT; i += 256) { scnt[i] = 0; soff[i] = 0; }
    __syncthreads();
    for (int k = 0; k < 4; ++k) {
        int idx4 = blockIdx.x * 1024 + k * 256 + threadIdx.x;
        if (idx4 < E4) {
            const int4 d = *reinterpret_cast<const int4*>(dst + idx4 * 4);
            atomicAdd(&scnt[d.x >> BSHIFT], 1);
            atomicAdd(&scnt[d.y >> BSHIFT], 1);
            atomicAdd(&scnt[d.z >> BSHIFT], 1);
            atomicAdd(&scnt[d.w >> BSHIFT], 1);
        }
    }
    __syncthreads();
    for (int i = threadIdx.x; i < NBKT; i += 256) {
        int c = scnt[i];
        if (c) sbase[i] = atomicAdd(&bkt_cursor[i], c);
    }
    __syncthreads();
    for (int k = 0; k < 4; ++k) {
        int idx4 = blockIdx.x * 1024 + k * 256 + threadIdx.x;
        if (idx4 < E4) {
            const int4 s = *reinterpret_cast<const int4*>(src + idx4 * 4);
            const int4 d = *reinterpret_cast<const int4*>(dst + idx4 * 4);
            int b, pos;
            b = d.x >> BSHIFT; pos = sbase[b] + atomicAdd(&soff[b], 1); pairs[pos] = make_int2(s.x, d.x);
            b = d.y >> BSHIFT; pos = sbase[b] + atomicAdd(&soff[b], 1); pairs[pos] = make_int2(s.y, d.y);
            b = d.z >> BSHIFT; pos = sbase[b] + atomicAdd(&soff[b], 1); pairs[pos] = make_int2(s.z, d.z);
            b = d.w >> BSHIFT; pos = sbase[b] + atomicAdd(&soff[b], 1); pairs[pos] = make_int2(s.w, d.w);
        }
    }
}

// ---- A2: counting-sort each dst-bucket's pairs by src-bucket (locality) ----
__global__ void sort_pairs_kernel(const int2* __restrict__ pairs,
                                  const int* __restrict__ bkt_base,
                                  int2* __restrict__ pairs2) {
    __shared__ int s[512];
    __shared__ int sbase[NBKT];
    __shared__ int soff[NBKT];
    const int b = blockIdx.x;
    const int beg = bkt_base[b];
    const int end = bkt_base[b + 1];
    s[threadIdx.x] = 0;
    if (threadIdx.x < NBKT) soff[threadIdx.x] = 0;
    __syncthreads();
    for (int j = beg + threadIdx.x; j < end; j += 512) {
        atomicAdd(&s[pairs[j].x >> BSHIFT], 1);
    }
    __syncthreads();
    int v = s[threadIdx.x];
    __syncthreads();
    for (int off = 1; off < 512; off <<= 1) {
        int t = (threadIdx.x >= off) ? s[threadIdx.x - off] : 0;
        __syncthreads();
        s[threadIdx.x] += t;
        __syncthreads();
    }
    if (threadIdx.x < NBKT) sbase[threadIdx.x] = s[threadIdx.x] - v;  // exclusive
    __syncthreads();
    for (int j = beg + threadIdx.x; j < end; j += 512) {
        int2 p = pairs[j];
        int sb = p.x >> BSHIFT;
        int pos = beg + sbase[sb] + atomicAdd(&soff[sb], 1);
        pairs2[pos] = p;
    }
}

// ---- B: per-bucket node counts (LDS), scan, rowptr/disq write, csr scatter ----
__global__ void build_csr_kernel(const int2* __restrict__ pairs,
                                 const int* __restrict__ bkt_base,
                                 int* __restrict__ rowptr, float* __restrict__ disq,
                                 int* __restrict__ csr_src) {
    __shared__ int scnt[BKT_NODES];
    __shared__ int ssc[BKT_NODES];
    __shared__ int scur[BKT_NODES];
    const int b = blockIdx.x;
    const int n0 = b << BSHIFT;
    const int nb = min(BKT_NODES, N_NODES - n0);
    const int beg = bkt_base[b];
    const int end = bkt_base[b + 1];
    scnt[threadIdx.x] = 0;
    __syncthreads();
    for (int j = beg + threadIdx.x; j < end; j += 256) {
        atomicAdd(&scnt[pairs[j].y - n0], 1);
    }
    __syncthreads();
    int v = scnt[threadIdx.x];
    ssc[threadIdx.x] = v;
    __syncthreads();
    for (int off = 1; off < 256; off <<= 1) {
        int t = (threadIdx.x >= off) ? ssc[threadIdx.x - off] : 0;
        __syncthreads();
        ssc[threadIdx.x] += t;
        __syncthreads();
    }
    int excl = ssc[threadIdx.x] - v;
    scur[threadIdx.x] = beg + excl;
    if (threadIdx.x < nb) {
        rowptr[n0 + threadIdx.x] = beg + excl;
        disq[n0 + threadIdx.x] = rsqrtf(1.0f + (float)v);
    }
    if (b == NBKT - 1 && threadIdx.x == 0) rowptr[N_NODES] = N_EDGES;
    __syncthreads();
    for (int j = beg + threadIdx.x; j < end; j += 256) {
        int2 p = pairs[j];
        int pos = atomicAdd(&scur[p.y - n0], 1);
        csr_src[pos] = p.x;
    }
}

// ---- MFMA linear: h_bf16 = in_f32 @ W_f32, fp32-accurate via hi/lo bf16 split ----
// in: [N][64] fp32; W: [64][D_OUT] fp32; h: [N][D_OUT] bf16.
// A-frag (16x16x32 bf16): lane holds A[l&15][(l>>4)*8 + j], j=0..7.
// B-frag: lane holds B[(l>>4)*8 + j][l&15]. D: row=(l>>4)*4+reg, col=l&15 (HW-verified).
template <int D_OUT>
__global__ __launch_bounds__(256) void linear_mfma_kernel(const float* __restrict__ in,
                                                          const float* __restrict__ W,
                                                          unsigned short* __restrict__ h) {
    constexpr int NCT = D_OUT / 16;       // col-tiles: 4 (D=64) or 2 (D=32)
    const int wave = threadIdx.x >> 6;
    const int lane = threadIdx.x & 63;
    const int lg = lane >> 4;             // k-group 0..3
    const int lm = lane & 15;             // m (A-row) / n (B-col / D-col)

    // pack W fragments (hi/lo bf16 split) into registers once
    short8 Bhi[NCT][2], Blo[NCT][2];
#pragma unroll
    for (int ct = 0; ct < NCT; ++ct)
#pragma unroll
        for (int kk = 0; kk < 2; ++kk)
#pragma unroll
            for (int j = 0; j < 8; ++j) {
                float wv = W[(kk * 32 + lg * 8 + j) * D_OUT + ct * 16 + lm];
                unsigned short hi = f2bf(wv);
                unsigned short lo = f2bf(wv - bf2f(hi));
                Bhi[ct][kk][j] = (short)hi;
                Blo[ct][kk][j] = (short)lo;
            }

    const int slot = blockIdx.x * 4 + wave;   // 391*4 = 1564 wave-slots
#pragma unroll 1
    for (int i = 0; i < 4; ++i) {
        int tile = slot + i * 1564;
        if (tile >= NTILES) break;
        int row = tile * 16 + lm;

        short8 Ahi[2], Alo[2];
#pragma unroll
        for (int kk = 0; kk < 2; ++kk) {
            const float4 v0 = *reinterpret_cast<const float4*>(in + (size_t)row * 64 + kk * 32 + lg * 8);
            const float4 v1 = *reinterpret_cast<const float4*>(in + (size_t)row * 64 + kk * 32 + lg * 8 + 4);
            float av[8] = {v0.x, v0.y, v0.z, v0.w, v1.x, v1.y, v1.z, v1.w};
#pragma unroll
            for (int j = 0; j < 8; ++j) {
                unsigned short hi = f2bf(av[j]);
                unsigned short lo = f2bf(av[j] - bf2f(hi));
                Ahi[kk][j] = (short)hi;
                Alo[kk][j] = (short)lo;
            }
        }

        float4v acc[NCT];
#pragma unroll
        for (int ct = 0; ct < NCT; ++ct) acc[ct] = (float4v){0.f, 0.f, 0.f, 0.f};

#pragma unroll
        for (int ct = 0; ct < NCT; ++ct)
#pragma unroll
            for (int kk = 0; kk < 2; ++kk) {
                acc[ct] = __builtin_amdgcn_mfma_f32_16x16x32_bf16(Ahi[kk], Bhi[ct][kk], acc[ct], 0, 0, 0);
                acc[ct] = __builtin_amdgcn_mfma_f32_16x16x32_bf16(Ahi[kk], Blo[ct][kk], acc[ct], 0, 0, 0);
                acc[ct] = __builtin_amdgcn_mfma_f32_16x16x32_bf16(Alo[kk], Bhi[ct][kk], acc[ct], 0, 0, 0);
            }

#pragma unroll
        for (int ct = 0; ct < NCT; ++ct)
#pragma unroll
            for (int r = 0; r < 4; ++r) {
                int orow = tile * 16 + lg * 4 + r;
                h[(size_t)orow * D_OUT + ct * 16 + lm] = f2bf(acc[ct][r]);
            }
    }
}

// ---- gather-reduce + fused finish (bf16 h) ----
// out = [relu]( disq[n] * ( sum_nbr disq[s]*h[s]  +  disq[n]*h[n] ) + b )
template <int D, bool RELU>
__global__ void gather_finish_kernel(const int* __restrict__ rowptr,
                                     const int* __restrict__ csr_src,
                                     const unsigned short* __restrict__ h,
                                     const float* __restrict__ disq,
                                     const float* __restrict__ b,
                                     float* __restrict__ out) {
    constexpr int TPN = D / 4;  // threads per node (4 cols each)
    int t = blockIdx.x * blockDim.x + threadIdx.x;
    int node = t / TPN;
    if (node >= N_NODES) return;
    int part = t % TPN;
    int beg = rowptr[node];
    int end = rowptr[node + 1];
    float4 a0 = {0.f, 0.f, 0.f, 0.f};
    float4 a1 = {0.f, 0.f, 0.f, 0.f};
    int j = beg;
    for (; j + 1 < end; j += 2) {
        int s0 = csr_src[j];
        int s1 = csr_src[j + 1];
        float w0 = disq[s0];
        float w1 = disq[s1];
        const ushort4 u0 = *reinterpret_cast<const ushort4*>(h + (size_t)s0 * D + part * 4);
        const ushort4 u1 = *reinterpret_cast<const ushort4*>(h + (size_t)s1 * D + part * 4);
        a0.x = fmaf(bf2f(u0.x), w0, a0.x); a1.x = fmaf(bf2f(u1.x), w1, a1.x);
        a0.y = fmaf(bf2f(u0.y), w0, a0.y); a1.y = fmaf(bf2f(u1.y), w1, a1.y);
        a0.z = fmaf(bf2f(u0.z), w0, a0.z); a1.z = fmaf(bf2f(u1.z), w1, a1.z);
        a0.w = fmaf(bf2f(u0.w), w0, a0.w); a1.w = fmaf(bf2f(u1.w), w1, a1.w);
    }
    if (j < end) {
        int s0 = csr_src[j];
        float w0 = disq[s0];
        const ushort4 u0 = *reinterpret_cast<const ushort4*>(h + (size_t)s0 * D + part * 4);
        a0.x = fmaf(bf2f(u0.x), w0, a0.x);
        a0.y = fmaf(bf2f(u0.y), w0, a0.y);
        a0.z = fmaf(bf2f(u0.z), w0, a0.z);
        a0.w = fmaf(bf2f(u0.w), w0, a0.w);
    }
    float dn = disq[node];
    const ushort4 hu = *reinterpret_cast<const ushort4*>(h + (size_t)node * D + part * 4);
    const float4 bv = *reinterpret_cast<const float4*>(b + part * 4);
    float4 acc;
    acc.x = fmaf(a0.x + a1.x + dn * bf2f(hu.x), dn, bv.x);
    acc.y = fmaf(a0.y + a1.y + dn * bf2f(hu.y), dn, bv.y);
    acc.z = fmaf(a0.z + a1.z + dn * bf2f(hu.z), dn, bv.z);
    acc.w = fmaf(a0.w + a1.w + dn * bf2f(hu.w), dn, bv.w);
    if (RELU) {
        acc.x = (acc.x >= 0.f) ? acc.x : NEG * acc.x;
        acc.y = (acc.y >= 0.f) ? acc.y : NEG * acc.y;
        acc.z = (acc.z >= 0.f) ? acc.z : NEG * acc.z;
        acc.w = (acc.w >= 0.f) ? acc.w : NEG * acc.w;
    }
    *reinterpret_cast<float4*>(out + (size_t)node * D + part * 4) = acc;
}

extern "C" void kernel_launch(void* const* d_in, const int* in_sizes, int n_in,
                              void* d_out, int out_size, void* d_ws, size_t ws_size,
                              hipStream_t stream) {
    const float* x  = (const float*)d_in[0];
    const int* ei   = (const int*)d_in[1];
    const int* src  = ei;            // edge_index[0]
    const int* dst  = ei + N_EDGES;  // edge_index[1]
    const float* W1 = (const float*)d_in[2];
    const float* b1 = (const float*)d_in[3];
    const float* W2 = (const float*)d_in[4];
    const float* b2 = (const float*)d_in[5];
    const float* W3 = (const float*)d_in[6];
    const float* b3 = (const float*)d_in[7];

    float* out  = (float*)d_out;
    float* emb1 = out;                          // N x 64
    float* emb2 = out + (size_t)N_NODES * 64;   // N x 64
    float* emb3 = out + (size_t)N_NODES * 128;  // N x 32

    char* ws = (char*)d_ws;
    int*   bkt_cnt    = (int*)ws;   ws += sizeof(int) * (NBKT + 1);
    int*   bkt_base   = (int*)ws;   ws += sizeof(int) * (NBKT + 1);
    int*   bkt_cursor = (int*)ws;   ws += sizeof(int) * (NBKT + 1);
    ws = (char*)(((size_t)ws + 255) & ~(size_t)255);
    float* disq       = (float*)ws; ws += sizeof(float) * N_NODES;
    int*   rowptr     = (int*)ws;   ws += sizeof(int) * (N_NODES + 1);
    ws = (char*)(((size_t)ws + 255) & ~(size_t)255);
    int2*  pairs      = (int2*)ws;  ws += sizeof(int2) * N_EDGES;
    int2*  pairs2     = (int2*)ws;  ws += sizeof(int2) * N_EDGES;
    int*   csr_src    = (int*)ws;   ws += sizeof(int) * N_EDGES;
    unsigned short* h = (unsigned short*)ws; ws += sizeof(unsigned short) * (size_t)N_NODES * 64;

    const int BLK = 256;
    const int gN16  = (N_NODES * 16 + BLK - 1) / BLK;  // gather D=64
    const int gN8   = (N_NODES * 8  + BLK - 1) / BLK;  // gather D=32
    const int gMFMA = 391;  // 4 waves/block x 4 tiles/wave covers 6250 tiles

    // ---- CSR build (once; reused by all 3 layers) ----
    hipMemsetAsync(bkt_cnt, 0, sizeof(int) * (NBKT + 1), stream);
    bucket_count_kernel<<<ABLK, BLK, 0, stream>>>(dst, bkt_cnt);
    bucket_scan_kernel<<<1, 512, 0, stream>>>(bkt_cnt, bkt_base, bkt_cursor);
    bin_kernel<<<ABLK, BLK, 0, stream>>>(src, dst, bkt_cursor, pairs);
    sort_pairs_kernel<<<NBKT, 512, 0, stream>>>(pairs, bkt_base, pairs2);
    build_csr_kernel<<<NBKT, BLK, 0, stream>>>(pairs2, bkt_base, rowptr, disq, csr_src);

    // ---- layer 1: x[64] -> emb1[64], leaky_relu ----
    linear_mfma_kernel<64><<<gMFMA, BLK, 0, stream>>>(x, W1, h);
    gather_finish_kernel<64, true><<<gN16, BLK, 0, stream>>>(rowptr, csr_src, h, disq, b1, emb1);

    // ---- layer 2: emb1[64] -> emb2[64], leaky_relu ----
    linear_mfma_kernel<64><<<gMFMA, BLK, 0, stream>>>(emb1, W2, h);
    gather_finish_kernel<64, true><<<gN16, BLK, 0, stream>>>(rowptr, csr_src, h, disq, b2, emb2);

    // ---- layer 3: emb2[64] -> emb3[32], no activation ----
    linear_mfma_kernel<32><<<gMFMA, BLK, 0, stream>>>(emb2, W3, h);
    gather_finish_kernel<32, false><<<gN8, BLK, 0, stream>>>(rowptr, csr_src, h, disq, b3, emb3);
}

// Round 8
// 274.691 us; speedup vs baseline: 13.6895x; 1.1011x over previous
//
#include <hip/hip_runtime.h>

// GCN_80376017977701: 3-layer GCN, N=100000, E=1600000, dims 64->64->64->32,
// symmetric norm with self-loops, leaky_relu(0.01) between layers.
// R7 (resubmit; prior round hit GPU acquisition timeout):
//   (a) h stored PRE-SCALED: h'[s] = disq[s]*h[s] (bf16) -> gather inner loop
//       is {load src, load row, add}: no disq load, no fmul.
//   (b) TPN=8 (ushort8, 16B/lane) + 4-edge batches -> 8x the lines in flight.
// CSR build unchanged from R6 (bucket bin + src-sort + per-bucket build).

constexpr int N_NODES = 100000;
constexpr int N_EDGES = 1600000;
constexpr int E4 = N_EDGES / 4;          // 400000 int4 elements
constexpr float NEG = 0.01f;

constexpr int BSHIFT = 8;                 // 256 nodes per bucket
constexpr int BKT_NODES = 1 << BSHIFT;
constexpr int NBKT = (N_NODES + BKT_NODES - 1) >> BSHIFT;  // 391
constexpr int EPB = 4096;                 // edges per bin/count block
constexpr int ABLK = (N_EDGES + EPB - 1) / EPB;            // 391 blocks

constexpr int NTILES = N_NODES / 16;      // 6250 (exact)

using short8 = __attribute__((ext_vector_type(8))) short;
using ushort8 = __attribute__((ext_vector_type(8))) unsigned short;
using float4v = __attribute__((ext_vector_type(4))) float;

// ---- bf16 helpers ----
__device__ __forceinline__ unsigned short f2bf(float f) {
    unsigned u = __float_as_uint(f);
    unsigned r = (u + 0x7fffu + ((u >> 16) & 1u)) >> 16;  // round-nearest-even
    return (unsigned short)r;
}
__device__ __forceinline__ float bf2f(unsigned short us) {
    return __uint_as_float(((unsigned)us) << 16);
}

// ---- A0: per-bucket edge counts (LDS-aggregated) ----
__global__ void bucket_count_kernel(const int* __restrict__ dst, int* __restrict__ bkt_cnt) {
    __shared__ int sc[NBKT];
    for (int i = threadIdx.x; i < NBKT; i += 256) sc[i] = 0;
    __syncthreads();
    for (int k = 0; k < 4; ++k) {
        int idx4 = blockIdx.x * 1024 + k * 256 + threadIdx.x;
        if (idx4 < E4) {
            const int4 d = *reinterpret_cast<const int4*>(dst + idx4 * 4);
            atomicAdd(&sc[d.x >> BSHIFT], 1);
            atomicAdd(&sc[d.y >> BSHIFT], 1);
            atomicAdd(&sc[d.z >> BSHIFT], 1);
            atomicAdd(&sc[d.w >> BSHIFT], 1);
        }
    }
    __syncthreads();
    for (int i = threadIdx.x; i < NBKT; i += 256) {
        int c = sc[i];
        if (c) atomicAdd(&bkt_cnt[i], c);
    }
}

// ---- exclusive scan over NBKT bucket counts (single block of 512) ----
__global__ void bucket_scan_kernel(const int* __restrict__ bkt_cnt,
                                   int* __restrict__ bkt_base, int* __restrict__ bkt_cursor) {
    __shared__ int s[512];
    int v = (threadIdx.x < NBKT) ? bkt_cnt[threadIdx.x] : 0;
    s[threadIdx.x] = v;
    __syncthreads();
    for (int off = 1; off < 512; off <<= 1) {
        int t = (threadIdx.x >= off) ? s[threadIdx.x - off] : 0;
        __syncthreads();
        s[threadIdx.x] += t;
        __syncthreads();
    }
    if (threadIdx.x < NBKT) {
        int b = s[threadIdx.x] - v;      // exclusive
        bkt_base[threadIdx.x] = b;
        bkt_cursor[threadIdx.x] = b;
    }
    if (threadIdx.x == NBKT) bkt_base[NBKT] = N_EDGES;
}

// ---- A1: bin edges into bucket-grouped (src,dst) pair storage ----
__global__ void bin_kernel(const int* __restrict__ src, const int* __restrict__ dst,
                           int* __restrict__ bkt_cursor, int2* __restrict__ pairs) {
    __shared__ int scnt[NBKT];
    __shared__ int sbase[NBKT];
    __shared__ int soff[NBKT];
    for (int i = threadIdx.x; i < NBKT; i += 256) { scnt[i] = 0; soff[i] = 0; }
    __syncthreads();
    for (int k = 0; k < 4; ++k) {
        int idx4 = blockIdx.x * 1024 + k * 256 + threadIdx.x;
        if (idx4 < E4) {
            const int4 d = *reinterpret_cast<const int4*>(dst + idx4 * 4);
            atomicAdd(&scnt[d.x >> BSHIFT], 1);
            atomicAdd(&scnt[d.y >> BSHIFT], 1);
            atomicAdd(&scnt[d.z >> BSHIFT], 1);
            atomicAdd(&scnt[d.w >> BSHIFT], 1);
        }
    }
    __syncthreads();
    for (int i = threadIdx.x; i < NBKT; i += 256) {
        int c = scnt[i];
        if (c) sbase[i] = atomicAdd(&bkt_cursor[i], c);
    }
    __syncthreads();
    for (int k = 0; k < 4; ++k) {
        int idx4 = blockIdx.x * 1024 + k * 256 + threadIdx.x;
        if (idx4 < E4) {
            const int4 s = *reinterpret_cast<const int4*>(src + idx4 * 4);
            const int4 d = *reinterpret_cast<const int4*>(dst + idx4 * 4);
            int b, pos;
            b = d.x >> BSHIFT; pos = sbase[b] + atomicAdd(&soff[b], 1); pairs[pos] = make_int2(s.x, d.x);
            b = d.y >> BSHIFT; pos = sbase[b] + atomicAdd(&soff[b], 1); pairs[pos] = make_int2(s.y, d.y);
            b = d.z >> BSHIFT; pos = sbase[b] + atomicAdd(&soff[b], 1); pairs[pos] = make_int2(s.z, d.z);
            b = d.w >> BSHIFT; pos = sbase[b] + atomicAdd(&soff[b], 1); pairs[pos] = make_int2(s.w, d.w);
        }
    }
}

// ---- A2: counting-sort each dst-bucket's pairs by src-bucket (locality) ----
__global__ void sort_pairs_kernel(const int2* __restrict__ pairs,
                                  const int* __restrict__ bkt_base,
                                  int2* __restrict__ pairs2) {
    __shared__ int s[512];
    __shared__ int sbase[NBKT];
    __shared__ int soff[NBKT];
    const int b = blockIdx.x;
    const int beg = bkt_base[b];
    const int end = bkt_base[b + 1];
    s[threadIdx.x] = 0;
    if (threadIdx.x < NBKT) soff[threadIdx.x] = 0;
    __syncthreads();
    for (int j = beg + threadIdx.x; j < end; j += 512) {
        atomicAdd(&s[pairs[j].x >> BSHIFT], 1);
    }
    __syncthreads();
    int v = s[threadIdx.x];
    __syncthreads();
    for (int off = 1; off < 512; off <<= 1) {
        int t = (threadIdx.x >= off) ? s[threadIdx.x - off] : 0;
        __syncthreads();
        s[threadIdx.x] += t;
        __syncthreads();
    }
    if (threadIdx.x < NBKT) sbase[threadIdx.x] = s[threadIdx.x] - v;  // exclusive
    __syncthreads();
    for (int j = beg + threadIdx.x; j < end; j += 512) {
        int2 p = pairs[j];
        int sb = p.x >> BSHIFT;
        int pos = beg + sbase[sb] + atomicAdd(&soff[sb], 1);
        pairs2[pos] = p;
    }
}

// ---- B: per-bucket node counts (LDS), scan, rowptr/disq write, csr scatter ----
__global__ void build_csr_kernel(const int2* __restrict__ pairs,
                                 const int* __restrict__ bkt_base,
                                 int* __restrict__ rowptr, float* __restrict__ disq,
                                 int* __restrict__ csr_src) {
    __shared__ int scnt[BKT_NODES];
    __shared__ int ssc[BKT_NODES];
    __shared__ int scur[BKT_NODES];
    const int b = blockIdx.x;
    const int n0 = b << BSHIFT;
    const int nb = min(BKT_NODES, N_NODES - n0);
    const int beg = bkt_base[b];
    const int end = bkt_base[b + 1];
    scnt[threadIdx.x] = 0;
    __syncthreads();
    for (int j = beg + threadIdx.x; j < end; j += 256) {
        atomicAdd(&scnt[pairs[j].y - n0], 1);
    }
    __syncthreads();
    int v = scnt[threadIdx.x];
    ssc[threadIdx.x] = v;
    __syncthreads();
    for (int off = 1; off < 256; off <<= 1) {
        int t = (threadIdx.x >= off) ? ssc[threadIdx.x - off] : 0;
        __syncthreads();
        ssc[threadIdx.x] += t;
        __syncthreads();
    }
    int excl = ssc[threadIdx.x] - v;
    scur[threadIdx.x] = beg + excl;
    if (threadIdx.x < nb) {
        rowptr[n0 + threadIdx.x] = beg + excl;
        disq[n0 + threadIdx.x] = rsqrtf(1.0f + (float)v);
    }
    if (b == NBKT - 1 && threadIdx.x == 0) rowptr[N_NODES] = N_EDGES;
    __syncthreads();
    for (int j = beg + threadIdx.x; j < end; j += 256) {
        int2 p = pairs[j];
        int pos = atomicAdd(&scur[p.y - n0], 1);
        csr_src[pos] = p.x;
    }
}

// ---- MFMA linear: h_bf16 = disq[row] * (in_f32 @ W_f32), hi/lo bf16 split ----
template <int D_OUT>
__global__ __launch_bounds__(256) void linear_mfma_kernel(const float* __restrict__ in,
                                                          const float* __restrict__ W,
                                                          const float* __restrict__ disq,
                                                          unsigned short* __restrict__ h) {
    constexpr int NCT = D_OUT / 16;       // col-tiles: 4 (D=64) or 2 (D=32)
    const int wave = threadIdx.x >> 6;
    const int lane = threadIdx.x & 63;
    const int lg = lane >> 4;             // k-group 0..3
    const int lm = lane & 15;             // m (A-row) / n (B-col / D-col)

    short8 Bhi[NCT][2], Blo[NCT][2];
#pragma unroll
    for (int ct = 0; ct < NCT; ++ct)
#pragma unroll
        for (int kk = 0; kk < 2; ++kk)
#pragma unroll
            for (int j = 0; j < 8; ++j) {
                float wv = W[(kk * 32 + lg * 8 + j) * D_OUT + ct * 16 + lm];
                unsigned short hi = f2bf(wv);
                unsigned short lo = f2bf(wv - bf2f(hi));
                Bhi[ct][kk][j] = (short)hi;
                Blo[ct][kk][j] = (short)lo;
            }

    const int slot = blockIdx.x * 4 + wave;   // 391*4 = 1564 wave-slots
#pragma unroll 1
    for (int i = 0; i < 4; ++i) {
        int tile = slot + i * 1564;
        if (tile >= NTILES) break;
        int row = tile * 16 + lm;

        short8 Ahi[2], Alo[2];
#pragma unroll
        for (int kk = 0; kk < 2; ++kk) {
            const float4 v0 = *reinterpret_cast<const float4*>(in + (size_t)row * 64 + kk * 32 + lg * 8);
            const float4 v1 = *reinterpret_cast<const float4*>(in + (size_t)row * 64 + kk * 32 + lg * 8 + 4);
            float av[8] = {v0.x, v0.y, v0.z, v0.w, v1.x, v1.y, v1.z, v1.w};
#pragma unroll
            for (int j = 0; j < 8; ++j) {
                unsigned short hi = f2bf(av[j]);
                unsigned short lo = f2bf(av[j] - bf2f(hi));
                Ahi[kk][j] = (short)hi;
                Alo[kk][j] = (short)lo;
            }
        }

        float4v acc[NCT];
#pragma unroll
        for (int ct = 0; ct < NCT; ++ct) acc[ct] = (float4v){0.f, 0.f, 0.f, 0.f};

#pragma unroll
        for (int ct = 0; ct < NCT; ++ct)
#pragma unroll
            for (int kk = 0; kk < 2; ++kk) {
                acc[ct] = __builtin_amdgcn_mfma_f32_16x16x32_bf16(Ahi[kk], Bhi[ct][kk], acc[ct], 0, 0, 0);
                acc[ct] = __builtin_amdgcn_mfma_f32_16x16x32_bf16(Ahi[kk], Blo[ct][kk], acc[ct], 0, 0, 0);
                acc[ct] = __builtin_amdgcn_mfma_f32_16x16x32_bf16(Alo[kk], Bhi[ct][kk], acc[ct], 0, 0, 0);
            }

#pragma unroll
        for (int r = 0; r < 4; ++r) {
            int orow = tile * 16 + lg * 4 + r;
            float dr = disq[orow];
#pragma unroll
            for (int ct = 0; ct < NCT; ++ct) {
                h[(size_t)orow * D_OUT + ct * 16 + lm] = f2bf(acc[ct][r] * dr);
            }
        }
    }
}

// ---- gather-reduce + fused finish (pre-scaled bf16 h') ----
// out = [relu]( disq[n] * ( sum_nbr h'[s] + h'[n] ) + b ),  h' = disq*h
template <int D, bool RELU>
__global__ __launch_bounds__(256) void gather_finish_kernel(const int* __restrict__ rowptr,
                                     const int* __restrict__ csr_src,
                                     const unsigned short* __restrict__ h,
                                     const float* __restrict__ disq,
                                     const float* __restrict__ b,
                                     float* __restrict__ out) {
    constexpr int TPN = D / 8;  // lanes per node, 8 cols (16B) each
    int t = blockIdx.x * blockDim.x + threadIdx.x;
    int node = t / TPN;
    if (node >= N_NODES) return;
    int part = t % TPN;
    const unsigned short* hp = h + part * 8;
    int beg = rowptr[node];
    int end = rowptr[node + 1];
    float acc0[8], acc1[8];
#pragma unroll
    for (int k = 0; k < 8; ++k) { acc0[k] = 0.f; acc1[k] = 0.f; }
    int j = beg;
    for (; j + 3 < end; j += 4) {
        int s0 = csr_src[j];
        int s1 = csr_src[j + 1];
        int s2 = csr_src[j + 2];
        int s3 = csr_src[j + 3];
        const ushort8 u0 = *reinterpret_cast<const ushort8*>(hp + (size_t)s0 * D);
        const ushort8 u1 = *reinterpret_cast<const ushort8*>(hp + (size_t)s1 * D);
        const ushort8 u2 = *reinterpret_cast<const ushort8*>(hp + (size_t)s2 * D);
        const ushort8 u3 = *reinterpret_cast<const ushort8*>(hp + (size_t)s3 * D);
#pragma unroll
        for (int k = 0; k < 8; ++k) {
            acc0[k] += bf2f(u0[k]) + bf2f(u2[k]);
            acc1[k] += bf2f(u1[k]) + bf2f(u3[k]);
        }
    }
    for (; j < end; ++j) {
        int s0 = csr_src[j];
        const ushort8 u0 = *reinterpret_cast<const ushort8*>(hp + (size_t)s0 * D);
#pragma unroll
        for (int k = 0; k < 8; ++k) acc0[k] += bf2f(u0[k]);
    }
    float dn = disq[node];
    const ushort8 un = *reinterpret_cast<const ushort8*>(hp + (size_t)node * D);
    float res[8];
#pragma unroll
    for (int k = 0; k < 8; ++k) {
        float bv = b[part * 8 + k];
        float v = fmaf(acc0[k] + acc1[k] + bf2f(un[k]), dn, bv);
        if (RELU) v = (v >= 0.f) ? v : NEG * v;
        res[k] = v;
    }
    float4 lo = {res[0], res[1], res[2], res[3]};
    float4 hi = {res[4], res[5], res[6], res[7]};
    float* op = out + (size_t)node * D + part * 8;
    *reinterpret_cast<float4*>(op) = lo;
    *reinterpret_cast<float4*>(op + 4) = hi;
}

extern "C" void kernel_launch(void* const* d_in, const int* in_sizes, int n_in,
                              void* d_out, int out_size, void* d_ws, size_t ws_size,
                              hipStream_t stream) {
    const float* x  = (const float*)d_in[0];
    const int* ei   = (const int*)d_in[1];
    const int* src  = ei;            // edge_index[0]
    const int* dst  = ei + N_EDGES;  // edge_index[1]
    const float* W1 = (const float*)d_in[2];
    const float* b1 = (const float*)d_in[3];
    const float* W2 = (const float*)d_in[4];
    const float* b2 = (const float*)d_in[5];
    const float* W3 = (const float*)d_in[6];
    const float* b3 = (const float*)d_in[7];

    float* out  = (float*)d_out;
    float* emb1 = out;                          // N x 64
    float* emb2 = out + (size_t)N_NODES * 64;   // N x 64
    float* emb3 = out + (size_t)N_NODES * 128;  // N x 32

    char* ws = (char*)d_ws;
    int*   bkt_cnt    = (int*)ws;   ws += sizeof(int) * (NBKT + 1);
    int*   bkt_base   = (int*)ws;   ws += sizeof(int) * (NBKT + 1);
    int*   bkt_cursor = (int*)ws;   ws += sizeof(int) * (NBKT + 1);
    ws = (char*)(((size_t)ws + 255) & ~(size_t)255);
    float* disq       = (float*)ws; ws += sizeof(float) * N_NODES;
    int*   rowptr     = (int*)ws;   ws += sizeof(int) * (N_NODES + 1);
    ws = (char*)(((size_t)ws + 255) & ~(size_t)255);
    int2*  pairs      = (int2*)ws;  ws += sizeof(int2) * N_EDGES;
    int2*  pairs2     = (int2*)ws;  ws += sizeof(int2) * N_EDGES;
    int*   csr_src    = (int*)ws;   ws += sizeof(int) * N_EDGES;
    unsigned short* h = (unsigned short*)ws; ws += sizeof(unsigned short) * (size_t)N_NODES * 64;

    const int BLK = 256;
    const int gG64 = (N_NODES * 8 + BLK - 1) / BLK;   // gather D=64 (TPN=8)
    const int gG32 = (N_NODES * 4 + BLK - 1) / BLK;   // gather D=32 (TPN=4)
    const int gMFMA = 391;  // 4 waves/block x 4 tiles/wave covers 6250 tiles

    // ---- CSR build (once; reused by all 3 layers) ----
    hipMemsetAsync(bkt_cnt, 0, sizeof(int) * (NBKT + 1), stream);
    bucket_count_kernel<<<ABLK, BLK, 0, stream>>>(dst, bkt_cnt);
    bucket_scan_kernel<<<1, 512, 0, stream>>>(bkt_cnt, bkt_base, bkt_cursor);
    bin_kernel<<<ABLK, BLK, 0, stream>>>(src, dst, bkt_cursor, pairs);
    sort_pairs_kernel<<<NBKT, 512, 0, stream>>>(pairs, bkt_base, pairs2);
    build_csr_kernel<<<NBKT, BLK, 0, stream>>>(pairs2, bkt_base, rowptr, disq, csr_src);

    // ---- layer 1: x[64] -> emb1[64], leaky_relu ----
    linear_mfma_kernel<64><<<gMFMA, BLK, 0, stream>>>(x, W1, disq, h);
    gather_finish_kernel<64, true><<<gG64, BLK, 0, stream>>>(rowptr, csr_src, h, disq, b1, emb1);

    // ---- layer 2: emb1[64] -> emb2[64], leaky_relu ----
    linear_mfma_kernel<64><<<gMFMA, BLK, 0, stream>>>(emb1, W2, disq, h);
    gather_finish_kernel<64, true><<<gG64, BLK, 0, stream>>>(rowptr, csr_src, h, disq, b2, emb2);

    // ---- layer 3: emb2[64] -> emb3[32], no activation ----
    linear_mfma_kernel<32><<<gMFMA, BLK, 0, stream>>>(emb2, W3, disq, h);
    gather_finish_kernel<32, false><<<gG32, BLK, 0, stream>>>(rowptr, csr_src, h, disq, b3, emb3);
}